// Round 7
// baseline (598.204 us; speedup 1.0000x reference)
//
#include <hip/hip_runtime.h>
#include <hip/hip_fp16.h>
#include <math.h>

#define N_NODES 40000
#define N_EDGES 640000
#define FIN 64
#define HID 128
#define OUTDIM 64
#define HEADS 4
#define NGROUPS 64
#define NCOLS 512   // HEADS*HID
#define NGRP (N_NODES / 4)   // aggregate node-groups (4 nodes each)

typedef _Float16 half8 __attribute__((ext_vector_type(8)));
typedef float f32x4 __attribute__((ext_vector_type(4)));

__device__ __forceinline__ float lrelu(float x) { return x > 0.f ? x : 0.2f * x; }

__device__ __forceinline__ void wave_lds_fence() {
    asm volatile("s_waitcnt lgkmcnt(0)" ::: "memory");
}

// ---------------- fp32 -> fp16 convert (x only) ----------------
__global__ void f32to16_kernel(const float* __restrict__ src, __half* __restrict__ dst, int n) {
    int i4 = (blockIdx.x * blockDim.x + threadIdx.x) * 4;
    if (i4 < n) {
        float4 v = *(const float4*)(src + i4);
        __half2 a = __floats2half2_rn(v.x, v.y);
        __half2 b = __floats2half2_rn(v.z, v.w);
        *(__half2*)(dst + i4)     = a;
        *(__half2*)(dst + i4 + 2) = b;
    }
}

// ------- weight transpose-convert: W_l fp32 [K][512] -> WT_l fp16 [512][K], all 3 ---
__global__ void wconv_kernel(const float* __restrict__ W0, const float* __restrict__ W1,
                             const float* __restrict__ W2,
                             _Float16* __restrict__ T0, _Float16* __restrict__ T1,
                             _Float16* __restrict__ T2) {
    int id = blockIdx.x * blockDim.x + threadIdx.x;
    int l = blockIdx.y;
    const float* W = (l == 0) ? W0 : (l == 1) ? W1 : W2;
    _Float16* T = (l == 0) ? T0 : (l == 1) ? T1 : T2;
    int K = (l == 0) ? FIN : HID;
    if (id >= NCOLS * (K / 8)) return;
    int col = id & (NCOLS - 1);
    int k8 = (id >> 9) * 8;
    half8 v;
    #pragma unroll
    for (int r = 0; r < 8; ++r)
        v[r] = (_Float16)W[(size_t)(k8 + r) * NCOLS + col];
    *(half8*)(T + (size_t)col * K + k8) = v;
}

// ------- scores via linearity: v[k][j] = sum_c W[k, h*128+c]*a_{s|d}[h,c]  (j=sd*4+h)
// all 3 layers in one launch: j index spans 64*8 + 128*8 + 128*8 = 2560
__global__ void prep_v_kernel(const float* __restrict__ W0, const float* __restrict__ as0, const float* __restrict__ ad0,
                              const float* __restrict__ W1, const float* __restrict__ as1, const float* __restrict__ ad1,
                              const float* __restrict__ W2, const float* __restrict__ as2, const float* __restrict__ ad2,
                              float* __restrict__ v0, float* __restrict__ v1, float* __restrict__ v2) {
    int j = blockIdx.x * blockDim.x + threadIdx.x;
    const float* W; const float* as_; const float* ad_; float* v; int K;
    if (j < FIN * 8)              { W = W0; as_ = as0; ad_ = ad0; v = v0; K = FIN; }
    else if (j < (FIN + HID) * 8) { W = W1; as_ = as1; ad_ = ad1; v = v1; K = HID; j -= FIN * 8; }
    else if (j < (FIN + 2 * HID) * 8) { W = W2; as_ = as2; ad_ = ad2; v = v2; K = HID; j -= (FIN + HID) * 8; }
    else return;
    int k = j >> 3, sd = (j >> 2) & 1, h = j & 3;
    const float* av = sd ? ad_ : as_;
    float acc = 0.f;
    for (int c = 0; c < HID; ++c)
        acc += W[(size_t)k * NCOLS + h * HID + c] * av[h * HID + c];
    v[k * 8 + sd * 4 + h] = acc;
}

// ---------------- CSR build ----------------
__global__ void deg_count_kernel(const int* __restrict__ ei, int* deg) {
    int e = blockIdx.x * blockDim.x + threadIdx.x;
    if (e < N_EDGES) atomicAdd(&deg[ei[N_EDGES + e]], 1);
}

__global__ void scan1_kernel(const int* __restrict__ deg, int* offsets, int* partial) {
    __shared__ int buf[256];
    int t = threadIdx.x;
    int i = blockIdx.x * 256 + t;
    int v = (i < N_NODES) ? deg[i] + 1 : 0;   // +1 = self loop
    buf[t] = v;
    __syncthreads();
    for (int off = 1; off < 256; off <<= 1) {
        int y = (t >= off) ? buf[t - off] : 0;
        __syncthreads();
        buf[t] += y;
        __syncthreads();
    }
    if (i < N_NODES) offsets[i] = buf[t] - v;       // local exclusive
    if (t == 255) partial[blockIdx.x] = buf[255];
}

__global__ void scan2_kernel(int* partial, int nb) {
    __shared__ int buf[256];
    int t = threadIdx.x;
    int v = (t < nb) ? partial[t] : 0;
    buf[t] = v;
    __syncthreads();
    for (int off = 1; off < 256; off <<= 1) {
        int y = (t >= off) ? buf[t - off] : 0;
        __syncthreads();
        buf[t] += y;
        __syncthreads();
    }
    if (t < nb) partial[t] = buf[t] - v;            // exclusive block prefix
}

__global__ void scan3_kernel(int* offsets, int* pos, const int* __restrict__ partial) {
    int i = blockIdx.x * 256 + threadIdx.x;
    if (i < N_NODES) {
        int o = offsets[i] + partial[i >> 8];
        offsets[i] = o;
        pos[i] = o;
    }
    if (i == 0) offsets[N_NODES] = N_EDGES + N_NODES;
}

__global__ void scatter_kernel(const int* __restrict__ ei, int* pos, int* csr_src) {
    int i = blockIdx.x * blockDim.x + threadIdx.x;
    if (i < N_EDGES) {
        int s = ei[i];
        int d = ei[N_EDGES + i];
        csr_src[atomicAdd(&pos[d], 1)] = s;
    } else if (i < N_EDGES + N_NODES) {
        int nn = i - N_EDGES;
        csr_src[atomicAdd(&pos[nn], 1)] = nn;
    }
}

// ------- MFMA GEMM v2: C[M,512] = A16[M,K] @ W[K,512], 64x512 block tile ---------
// 8 waves (2m x 4n), wave tile 32x128. A staged in LDS once; B frags read directly
// from pre-transposed WT[col][K] (128KB, L2-resident). Fragment addressing identical
// to the r5-verified kernel (Bs[col][k] -> WT[col][k]).
template <int K>
__global__ __launch_bounds__(512) void gemm_f16_kernel(const __half* __restrict__ A,
                                                       const _Float16* __restrict__ WT,
                                                       __half* __restrict__ C) {
    __shared__ _Float16 As[64][K + 8];
    int bm = blockIdx.x * 64;
    int t = threadIdx.x;
    int lane = t & 63;
    int w = t >> 6;
    int wm = w >> 2;        // 0..1
    int wn = w & 3;         // 0..3
    int lr = lane & 15;
    int lk = (lane >> 4) * 8;

    if (K == 64) {
        int row = t >> 3, k8 = (t & 7) * 8;
        uint4 av = *(const uint4*)(A + (size_t)(bm + row) * 64 + k8);
        *(uint4*)&As[row][k8] = av;
    } else {  // K == 128
        int row = t >> 4, k8 = (t & 15) * 8;
        #pragma unroll
        for (int rr = 0; rr < 64; rr += 32) {
            uint4 av = *(const uint4*)(A + (size_t)(bm + row + rr) * 128 + k8);
            *(uint4*)&As[row + rr][k8] = av;
        }
    }
    __syncthreads();

    f32x4 acc[2][8] = {};
    #pragma unroll
    for (int k0 = 0; k0 < K; k0 += 32) {
        half8 af0 = *(const half8*)&As[wm * 32 + lr][k0 + lk];
        half8 af1 = *(const half8*)&As[wm * 32 + 16 + lr][k0 + lk];
        #pragma unroll
        for (int nn = 0; nn < 8; ++nn) {
            half8 bf = *(const half8*)(WT + (size_t)(wn * 128 + nn * 16 + lr) * K + k0 + lk);
            acc[0][nn] = __builtin_amdgcn_mfma_f32_16x16x32_f16(af0, bf, acc[0][nn], 0, 0, 0);
            acc[1][nn] = __builtin_amdgcn_mfma_f32_16x16x32_f16(af1, bf, acc[1][nn], 0, 0, 0);
        }
    }

    int lg = lane >> 4;
    #pragma unroll
    for (int m = 0; m < 2; ++m) {
        #pragma unroll
        for (int nn = 0; nn < 8; ++nn) {
            int col = wn * 128 + nn * 16 + lr;
            #pragma unroll
            for (int r = 0; r < 4; ++r) {
                int row = bm + wm * 32 + m * 16 + lg * 4 + r;
                C[(size_t)row * NCOLS + col] = __float2half(acc[m][nn][r]);
            }
        }
    }
}

// ------- s[n, j] = sum_k x16[n,k] * v[k,j]   (j: 0-3 src heads, 4-7 dst heads)
__global__ __launch_bounds__(256) void scores2_kernel(const __half* __restrict__ x,
                                                      const float* __restrict__ v,
                                                      float* __restrict__ ssrc,
                                                      float* __restrict__ sdst, int K) {
    int node = blockIdx.x * 32 + (threadIdx.x >> 3);
    int j = threadIdx.x & 7;
    if (node >= N_NODES) return;
    const __half* xr = x + (size_t)node * K;
    float acc = 0.f;
    for (int k0 = 0; k0 < K; k0 += 8) {
        uint4 u = *(const uint4*)(xr + k0);
        __half2* hp = (__half2*)&u;
        #pragma unroll
        for (int q = 0; q < 4; ++q) {
            float2 f = __half22float2(hp[q]);
            acc += f.x * v[(k0 + 2 * q) * 8 + j] + f.y * v[(k0 + 2 * q + 1) * 8 + j];
        }
    }
    if (j < 4) ssrc[node * 4 + j] = acc;
    else       sdst[node * 4 + (j - 4)] = acc;
}

// ---- wave-per-node aggregate, grid-stride over node groups ----
__device__ __forceinline__ void accum8(float* acc, uint4 u, float a) {
    __half2* hp = (__half2*)&u;
    #pragma unroll
    for (int q = 0; q < 4; ++q) {
        float2 f = __half22float2(hp[q]);
        acc[2 * q]     += a * f.x;
        acc[2 * q + 1] += a * f.y;
    }
}

__global__ __launch_bounds__(256) void aggregate_kernel(const __half* __restrict__ xh,
                                                        const float* __restrict__ s_src,
                                                        const float* __restrict__ s_dst,
                                                        const int* __restrict__ offsets,
                                                        const int* __restrict__ csr_src,
                                                        const float* __restrict__ bias,
                                                        const float* __restrict__ gamma,
                                                        const float* __restrict__ beta,
                                                        __half* __restrict__ h16out) {
    int wv = threadIdx.x >> 6;
    int lane = threadIdx.x & 63;
    int myh = lane >> 4;

    __shared__ int   srcs[4][64];
    __shared__ float alpha[4][64][4];

    const char* xb = (const char*)xh + lane * 16;   // lane covers halves [lane*8, lane*8+8)

    for (int g = blockIdx.x; g < NGRP; g += gridDim.x) {
        int n = g * 4 + wv;    // N_NODES = 4*NGRP exactly
        int start = offsets[n], end = offsets[n + 1];
        int deg = end - start;
        const float4 sd = *(const float4*)(s_dst + n * 4);

        float acc[8] = {};

        if (deg <= 64) {
            bool act = lane < deg;
            int src = act ? csr_src[start + lane] : 0;
            float4 ss = *(const float4*)(s_src + src * 4);
            float e0 = act ? lrelu(ss.x + sd.x) : -1e30f;
            float e1 = act ? lrelu(ss.y + sd.y) : -1e30f;
            float e2 = act ? lrelu(ss.z + sd.z) : -1e30f;
            float e3 = act ? lrelu(ss.w + sd.w) : -1e30f;
            float m0 = e0, m1 = e1, m2 = e2, m3 = e3;
            #pragma unroll
            for (int o = 32; o > 0; o >>= 1) {
                m0 = fmaxf(m0, __shfl_xor(m0, o));
                m1 = fmaxf(m1, __shfl_xor(m1, o));
                m2 = fmaxf(m2, __shfl_xor(m2, o));
                m3 = fmaxf(m3, __shfl_xor(m3, o));
            }
            float p0 = __expf(e0 - m0), p1 = __expf(e1 - m1);
            float p2 = __expf(e2 - m2), p3 = __expf(e3 - m3);
            float s0 = p0, s1 = p1, s2 = p2, s3 = p3;
            #pragma unroll
            for (int o = 32; o > 0; o >>= 1) {
                s0 += __shfl_xor(s0, o);
                s1 += __shfl_xor(s1, o);
                s2 += __shfl_xor(s2, o);
                s3 += __shfl_xor(s3, o);
            }
            f32x4 av = {p0 / s0, p1 / s1, p2 / s2, p3 / s3};
            srcs[wv][lane] = src;
            *(f32x4*)&alpha[wv][lane][0] = av;
            wave_lds_fence();

            int j = 0;
            for (; j + 4 <= deg; j += 4) {
                uint o0 = (uint)srcs[wv][j]     << 10;
                uint o1 = (uint)srcs[wv][j + 1] << 10;
                uint o2 = (uint)srcs[wv][j + 2] << 10;
                uint o3 = (uint)srcs[wv][j + 3] << 10;
                float a0 = alpha[wv][j][myh];
                float a1 = alpha[wv][j + 1][myh];
                float a2 = alpha[wv][j + 2][myh];
                float a3 = alpha[wv][j + 3][myh];
                uint4 u0 = *(const uint4*)(xb + o0);
                uint4 u1 = *(const uint4*)(xb + o1);
                uint4 u2 = *(const uint4*)(xb + o2);
                uint4 u3 = *(const uint4*)(xb + o3);
                accum8(acc, u0, a0);
                accum8(acc, u1, a1);
                accum8(acc, u2, a2);
                accum8(acc, u3, a3);
            }
            for (; j < deg; ++j) {
                uint o0 = (uint)srcs[wv][j] << 10;
                float a0 = alpha[wv][j][myh];
                uint4 u0 = *(const uint4*)(xb + o0);
                accum8(acc, u0, a0);
            }
            wave_lds_fence();   // gather reads done before next iteration overwrites
        } else {
            // generic chunked path (deg > 64): 3 passes over edges
            float m0 = -1e30f, m1 = -1e30f, m2 = -1e30f, m3 = -1e30f;
            for (int j0 = 0; j0 < deg; j0 += 64) {
                int j = j0 + lane;
                bool act = j < deg;
                int src = act ? csr_src[start + j] : 0;
                float4 ss = *(const float4*)(s_src + src * 4);
                m0 = fmaxf(m0, act ? lrelu(ss.x + sd.x) : -1e30f);
                m1 = fmaxf(m1, act ? lrelu(ss.y + sd.y) : -1e30f);
                m2 = fmaxf(m2, act ? lrelu(ss.z + sd.z) : -1e30f);
                m3 = fmaxf(m3, act ? lrelu(ss.w + sd.w) : -1e30f);
            }
            #pragma unroll
            for (int o = 32; o > 0; o >>= 1) {
                m0 = fmaxf(m0, __shfl_xor(m0, o));
                m1 = fmaxf(m1, __shfl_xor(m1, o));
                m2 = fmaxf(m2, __shfl_xor(m2, o));
                m3 = fmaxf(m3, __shfl_xor(m3, o));
            }
            float s0 = 0.f, s1 = 0.f, s2 = 0.f, s3 = 0.f;
            for (int j0 = 0; j0 < deg; j0 += 64) {
                int j = j0 + lane;
                bool act = j < deg;
                int src = act ? csr_src[start + j] : 0;
                float4 ss = *(const float4*)(s_src + src * 4);
                s0 += act ? __expf(lrelu(ss.x + sd.x) - m0) : 0.f;
                s1 += act ? __expf(lrelu(ss.y + sd.y) - m1) : 0.f;
                s2 += act ? __expf(lrelu(ss.z + sd.z) - m2) : 0.f;
                s3 += act ? __expf(lrelu(ss.w + sd.w) - m3) : 0.f;
            }
            #pragma unroll
            for (int o = 32; o > 0; o >>= 1) {
                s0 += __shfl_xor(s0, o);
                s1 += __shfl_xor(s1, o);
                s2 += __shfl_xor(s2, o);
                s3 += __shfl_xor(s3, o);
            }
            float i0 = 1.f / s0, i1 = 1.f / s1, i2 = 1.f / s2, i3 = 1.f / s3;
            for (int j0 = 0; j0 < deg; j0 += 64) {
                int j = j0 + lane;
                bool act = j < deg;
                int src = act ? csr_src[start + j] : 0;
                float4 ss = *(const float4*)(s_src + src * 4);
                f32x4 av;
                av[0] = act ? __expf(lrelu(ss.x + sd.x) - m0) * i0 : 0.f;
                av[1] = act ? __expf(lrelu(ss.y + sd.y) - m1) * i1 : 0.f;
                av[2] = act ? __expf(lrelu(ss.z + sd.z) - m2) * i2 : 0.f;
                av[3] = act ? __expf(lrelu(ss.w + sd.w) - m3) * i3 : 0.f;
                srcs[wv][lane] = src;
                *(f32x4*)&alpha[wv][lane][0] = av;
                wave_lds_fence();
                int cend = min(64, deg - j0);
                for (int jj = 0; jj < cend; ++jj) {
                    uint o0 = (uint)srcs[wv][jj] << 10;
                    float aa = alpha[wv][jj][myh];
                    uint4 ua = *(const uint4*)(xb + o0);
                    accum8(acc, ua, aa);
                }
                wave_lds_fence();
            }
        }

        // cross-head mean: lanes {l, l+16, l+32, l+48} hold same channels for heads 0..3
        #pragma unroll
        for (int r = 0; r < 8; ++r) {
            acc[r] += __shfl_xor(acc[r], 16);
            acc[r] += __shfl_xor(acc[r], 32);
        }
        if (lane < 16) {
            int cb = lane * 8;
            ushort us[8];
            #pragma unroll
            for (int r = 0; r < 8; ++r) {
                int c = cb + r;
                float o = acc[r] * 0.25f + bias[c];
                o = o * (gamma[c] * rsqrtf(1.f + 1e-5f)) + beta[c];
                o = fmaxf(o, 0.f);
                us[r] = __half_as_ushort(__float2half(o));
            }
            uint4 pack;
            pack.x = (uint)us[0] | ((uint)us[1] << 16);
            pack.y = (uint)us[2] | ((uint)us[3] << 16);
            pack.z = (uint)us[4] | ((uint)us[5] << 16);
            pack.w = (uint)us[6] | ((uint)us[7] << 16);
            *(uint4*)(h16out + (size_t)n * HID + cb) = pack;
        }
    }
}

// ---------------- pooling (batch sorted -> run-length partial sums) ----------------
__global__ __launch_bounds__(128) void pool_kernel(const __half* __restrict__ h,
                                                   const int* __restrict__ batch,
                                                   float* pooled, float* counts) {
    int t = threadIdx.x;
    int n0 = blockIdx.x * 256;
    int n1 = min(n0 + 256, N_NODES);
    if (n0 >= N_NODES) return;
    int cg = batch[n0];
    float acc = 0.f, cnt = 0.f;
    for (int n = n0; n < n1; ++n) {
        int g = batch[n];
        if (g != cg) {
            atomicAdd(&pooled[cg * HID + t], acc);
            if (t == 0) atomicAdd(&counts[cg], cnt);
            acc = 0.f; cnt = 0.f; cg = g;
        }
        acc += __half2float(h[(size_t)n * HID + t]);
        cnt += 1.f;
    }
    atomicAdd(&pooled[cg * HID + t], acc);
    if (t == 0) atomicAdd(&counts[cg], cnt);
}

// ---------------- head: mean-divide + fc1 + relu + fc2 ----------------
__global__ __launch_bounds__(128) void head_kernel(const float* __restrict__ pooled,
                                                   const float* __restrict__ counts,
                                                   const float* __restrict__ fc1_w,
                                                   const float* __restrict__ fc1_b,
                                                   const float* __restrict__ fc2_w,
                                                   const float* __restrict__ fc2_b,
                                                   float* __restrict__ out) {
    int gI = blockIdx.x;
    int t = threadIdx.x;
    __shared__ float p[HID], hb[HID];
    p[t] = pooled[gI * HID + t] / fmaxf(counts[gI], 1.f);
    __syncthreads();
    float a = fc1_b[t];
    #pragma unroll 4
    for (int k = 0; k < HID; ++k) a += p[k] * fc1_w[k * HID + t];
    hb[t] = fmaxf(a, 0.f);
    __syncthreads();
    if (t < OUTDIM) {
        float o = fc2_b[t];
        #pragma unroll 4
        for (int k = 0; k < HID; ++k) o += hb[k] * fc2_w[k * OUTDIM + t];
        out[gI * OUTDIM + t] = o;
    }
}

extern "C" void kernel_launch(void* const* d_in, const int* in_sizes, int n_in,
                              void* d_out, int out_size, void* d_ws, size_t ws_size,
                              hipStream_t stream) {
    const float* x     = (const float*)d_in[0];
    const int*   ei    = (const int*)d_in[1];
    const int*   batch = (const int*)d_in[2];
    const float* W[3]  = {(const float*)d_in[3],  (const float*)d_in[9],  (const float*)d_in[15]};
    const float* As[3] = {(const float*)d_in[4],  (const float*)d_in[10], (const float*)d_in[16]};
    const float* Ad[3] = {(const float*)d_in[5],  (const float*)d_in[11], (const float*)d_in[17]};
    const float* Bb[3] = {(const float*)d_in[6],  (const float*)d_in[12], (const float*)d_in[18]};
    const float* Gg[3] = {(const float*)d_in[7],  (const float*)d_in[13], (const float*)d_in[19]};
    const float* Be[3] = {(const float*)d_in[8],  (const float*)d_in[14], (const float*)d_in[20]};
    const float* fc1_w = (const float*)d_in[21];
    const float* fc1_b = (const float*)d_in[22];
    const float* fc2_w = (const float*)d_in[23];
    const float* fc2_b = (const float*)d_in[24];

    char* ws = (char*)d_ws;
    size_t off = 0;
    auto alloc = [&](size_t bytes) {
        void* p = ws + off;
        off = (off + bytes + 255) & ~(size_t)255;
        return p;
    };
    __half* xh     = (__half*)alloc((size_t)N_NODES * NCOLS * 2);
    __half* x16    = (__half*)alloc((size_t)N_NODES * FIN * 2);
    __half* h16    = (__half*)alloc((size_t)N_NODES * HID * 2);
    _Float16* WT[3];
    WT[0] = (_Float16*)alloc((size_t)NCOLS * FIN * 2);
    WT[1] = (_Float16*)alloc((size_t)NCOLS * HID * 2);
    WT[2] = (_Float16*)alloc((size_t)NCOLS * HID * 2);
    float* vtab[3];
    vtab[0] = (float*)alloc((size_t)FIN * 8 * 4);
    vtab[1] = (float*)alloc((size_t)HID * 8 * 4);
    vtab[2] = (float*)alloc((size_t)HID * 8 * 4);
    float* ssrc    = (float*)alloc((size_t)N_NODES * HEADS * 4);
    float* sdst    = (float*)alloc((size_t)N_NODES * HEADS * 4);
    int*   deg     = (int*)alloc((size_t)N_NODES * 4);
    int*   offsets = (int*)alloc((size_t)(N_NODES + 1) * 4);
    int*   pos     = (int*)alloc((size_t)N_NODES * 4);
    int*   partial = (int*)alloc((size_t)256 * 4);
    int*   csr     = (int*)alloc((size_t)(N_EDGES + N_NODES) * 4);
    float* pooled  = (float*)alloc((size_t)NGROUPS * HID * 4);
    float* counts  = (float*)alloc((size_t)NGROUPS * 4);

    // conversions + per-layer score vectors
    f32to16_kernel<<<(N_NODES * FIN / 4 + 255) / 256, 256, 0, stream>>>(x, x16, N_NODES * FIN);
    wconv_kernel<<<dim3((NCOLS * HID / 8 + 255) / 256, 3), 256, 0, stream>>>(
        W[0], W[1], W[2], WT[0], WT[1], WT[2]);
    prep_v_kernel<<<((FIN + 2 * HID) * 8 + 255) / 256, 256, 0, stream>>>(
        W[0], As[0], Ad[0], W[1], As[1], Ad[1], W[2], As[2], Ad[2],
        vtab[0], vtab[1], vtab[2]);

    // CSR by dst (with self loops)
    const int NB = (N_NODES + 255) / 256;   // 157
    hipMemsetAsync(deg, 0, (size_t)N_NODES * 4, stream);
    deg_count_kernel<<<(N_EDGES + 255) / 256, 256, 0, stream>>>(ei, deg);
    scan1_kernel<<<NB, 256, 0, stream>>>(deg, offsets, partial);
    scan2_kernel<<<1, 256, 0, stream>>>(partial, NB);
    scan3_kernel<<<NB, 256, 0, stream>>>(offsets, pos, partial);
    scatter_kernel<<<(N_EDGES + N_NODES + 255) / 256, 256, 0, stream>>>(ei, pos, csr);

    // 3 GAT layers
    const __half* Ain = x16;
    for (int l = 0; l < 3; ++l) {
        int K = (l == 0) ? FIN : HID;
        if (K == 64)
            gemm_f16_kernel<64><<<N_NODES / 64, 512, 0, stream>>>(Ain, WT[l], xh);
        else
            gemm_f16_kernel<128><<<N_NODES / 64, 512, 0, stream>>>(Ain, WT[l], xh);
        scores2_kernel<<<(N_NODES + 31) / 32, 256, 0, stream>>>(Ain, vtab[l], ssrc, sdst, K);
        aggregate_kernel<<<2048, 256, 0, stream>>>(xh, ssrc, sdst, offsets, csr,
                                                   Bb[l], Gg[l], Be[l], h16);
        Ain = h16;
    }

    // global mean pool + MLP head
    hipMemsetAsync(pooled, 0, (size_t)NGROUPS * HID * 4, stream);
    hipMemsetAsync(counts, 0, (size_t)NGROUPS * 4, stream);
    pool_kernel<<<(N_NODES + 255) / 256, 128, 0, stream>>>(h16, batch, pooled, counts);
    head_kernel<<<NGROUPS, 128, 0, stream>>>(pooled, counts, fc1_w, fc1_b, fc2_w, fc2_b,
                                             (float*)d_out);
}

// Round 8
// 571.922 us; speedup vs baseline: 1.0460x; 1.0460x over previous
//
#include <hip/hip_runtime.h>
#include <hip/hip_fp16.h>
#include <math.h>

#define N_NODES 40000
#define N_EDGES 640000
#define FIN 64
#define HID 128
#define OUTDIM 64
#define HEADS 4
#define NGROUPS 64
#define NCOLS 512   // HEADS*HID

typedef _Float16 half8 __attribute__((ext_vector_type(8)));
typedef float f32x4 __attribute__((ext_vector_type(4)));

__device__ __forceinline__ float lrelu(float x) { return x > 0.f ? x : 0.2f * x; }

__device__ __forceinline__ void wave_lds_fence() {
    asm volatile("s_waitcnt lgkmcnt(0)" ::: "memory");
}

// ---------------- fp32 -> fp16 convert (x only) ----------------
__global__ void f32to16_kernel(const float* __restrict__ src, __half* __restrict__ dst, int n) {
    int i4 = (blockIdx.x * blockDim.x + threadIdx.x) * 4;
    if (i4 < n) {
        float4 v = *(const float4*)(src + i4);
        __half2 a = __floats2half2_rn(v.x, v.y);
        __half2 b = __floats2half2_rn(v.z, v.w);
        *(__half2*)(dst + i4)     = a;
        *(__half2*)(dst + i4 + 2) = b;
    }
}

// ------- weight transpose-convert: W_l fp32 [K][512] -> WT_l fp16 [512][K], all 3 ---
__global__ void wconv_kernel(const float* __restrict__ W0, const float* __restrict__ W1,
                             const float* __restrict__ W2,
                             _Float16* __restrict__ T0, _Float16* __restrict__ T1,
                             _Float16* __restrict__ T2) {
    int id = blockIdx.x * blockDim.x + threadIdx.x;
    int l = blockIdx.y;
    const float* W = (l == 0) ? W0 : (l == 1) ? W1 : W2;
    _Float16* T = (l == 0) ? T0 : (l == 1) ? T1 : T2;
    int K = (l == 0) ? FIN : HID;
    if (id >= NCOLS * (K / 8)) return;
    int col = id & (NCOLS - 1);
    int k8 = (id >> 9) * 8;
    half8 v;
    #pragma unroll
    for (int r = 0; r < 8; ++r)
        v[r] = (_Float16)W[(size_t)(k8 + r) * NCOLS + col];
    *(half8*)(T + (size_t)col * K + k8) = v;
}

// ------- scores via linearity: v[k][j] = sum_c W[k, h*128+c]*a_{s|d}[h,c]  (j=sd*4+h)
__global__ void prep_v_kernel(const float* __restrict__ W0, const float* __restrict__ as0, const float* __restrict__ ad0,
                              const float* __restrict__ W1, const float* __restrict__ as1, const float* __restrict__ ad1,
                              const float* __restrict__ W2, const float* __restrict__ as2, const float* __restrict__ ad2,
                              float* __restrict__ v0, float* __restrict__ v1, float* __restrict__ v2) {
    int j = blockIdx.x * blockDim.x + threadIdx.x;
    const float* W; const float* as_; const float* ad_; float* v; int K;
    if (j < FIN * 8)              { W = W0; as_ = as0; ad_ = ad0; v = v0; K = FIN; }
    else if (j < (FIN + HID) * 8) { W = W1; as_ = as1; ad_ = ad1; v = v1; K = HID; j -= FIN * 8; }
    else if (j < (FIN + 2 * HID) * 8) { W = W2; as_ = as2; ad_ = ad2; v = v2; K = HID; j -= (FIN + HID) * 8; }
    else return;
    int k = j >> 3, sd = (j >> 2) & 1, h = j & 3;
    const float* av = sd ? ad_ : as_;
    float acc = 0.f;
    for (int c = 0; c < HID; ++c)
        acc += W[(size_t)k * NCOLS + h * HID + c] * av[h * HID + c];
    v[k * 8 + sd * 4 + h] = acc;
}

// ---------------- CSR build ----------------
__global__ void deg_count_kernel(const int* __restrict__ ei, int* deg) {
    int e = blockIdx.x * blockDim.x + threadIdx.x;
    if (e < N_EDGES) atomicAdd(&deg[ei[N_EDGES + e]], 1);
}

__global__ void scan1_kernel(const int* __restrict__ deg, int* offsets, int* partial) {
    __shared__ int buf[256];
    int t = threadIdx.x;
    int i = blockIdx.x * 256 + t;
    int v = (i < N_NODES) ? deg[i] + 1 : 0;   // +1 = self loop
    buf[t] = v;
    __syncthreads();
    for (int off = 1; off < 256; off <<= 1) {
        int y = (t >= off) ? buf[t - off] : 0;
        __syncthreads();
        buf[t] += y;
        __syncthreads();
    }
    if (i < N_NODES) offsets[i] = buf[t] - v;       // local exclusive
    if (t == 255) partial[blockIdx.x] = buf[255];
}

__global__ void scan2_kernel(int* partial, int nb) {
    __shared__ int buf[256];
    int t = threadIdx.x;
    int v = (t < nb) ? partial[t] : 0;
    buf[t] = v;
    __syncthreads();
    for (int off = 1; off < 256; off <<= 1) {
        int y = (t >= off) ? buf[t - off] : 0;
        __syncthreads();
        buf[t] += y;
        __syncthreads();
    }
    if (t < nb) partial[t] = buf[t] - v;            // exclusive block prefix
}

__global__ void scan3_kernel(int* offsets, int* pos, const int* __restrict__ partial) {
    int i = blockIdx.x * 256 + threadIdx.x;
    if (i < N_NODES) {
        int o = offsets[i] + partial[i >> 8];
        offsets[i] = o;
        pos[i] = o;
    }
    if (i == 0) offsets[N_NODES] = N_EDGES + N_NODES;
}

__global__ void scatter_kernel(const int* __restrict__ ei, int* pos, int* csr_src) {
    int i = blockIdx.x * blockDim.x + threadIdx.x;
    if (i < N_EDGES) {
        int s = ei[i];
        int d = ei[N_EDGES + i];
        csr_src[atomicAdd(&pos[d], 1)] = s;
    } else if (i < N_EDGES + N_NODES) {
        int nn = i - N_EDGES;
        csr_src[atomicAdd(&pos[nn], 1)] = nn;
    }
}

// ------- MFMA GEMM v2: C[M,512] = A16[M,K] @ W[K,512], 64x512 block tile ---------
template <int K>
__global__ __launch_bounds__(512) void gemm_f16_kernel(const __half* __restrict__ A,
                                                       const _Float16* __restrict__ WT,
                                                       __half* __restrict__ C) {
    __shared__ _Float16 As[64][K + 8];
    int bm = blockIdx.x * 64;
    int t = threadIdx.x;
    int lane = t & 63;
    int w = t >> 6;
    int wm = w >> 2;        // 0..1
    int wn = w & 3;         // 0..3
    int lr = lane & 15;
    int lk = (lane >> 4) * 8;

    if (K == 64) {
        int row = t >> 3, k8 = (t & 7) * 8;
        uint4 av = *(const uint4*)(A + (size_t)(bm + row) * 64 + k8);
        *(uint4*)&As[row][k8] = av;
    } else {  // K == 128
        int row = t >> 4, k8 = (t & 15) * 8;
        #pragma unroll
        for (int rr = 0; rr < 64; rr += 32) {
            uint4 av = *(const uint4*)(A + (size_t)(bm + row + rr) * 128 + k8);
            *(uint4*)&As[row + rr][k8] = av;
        }
    }
    __syncthreads();

    f32x4 acc[2][8] = {};
    #pragma unroll
    for (int k0 = 0; k0 < K; k0 += 32) {
        half8 af0 = *(const half8*)&As[wm * 32 + lr][k0 + lk];
        half8 af1 = *(const half8*)&As[wm * 32 + 16 + lr][k0 + lk];
        #pragma unroll
        for (int nn = 0; nn < 8; ++nn) {
            half8 bf = *(const half8*)(WT + (size_t)(wn * 128 + nn * 16 + lr) * K + k0 + lk);
            acc[0][nn] = __builtin_amdgcn_mfma_f32_16x16x32_f16(af0, bf, acc[0][nn], 0, 0, 0);
            acc[1][nn] = __builtin_amdgcn_mfma_f32_16x16x32_f16(af1, bf, acc[1][nn], 0, 0, 0);
        }
    }

    int lg = lane >> 4;
    #pragma unroll
    for (int m = 0; m < 2; ++m) {
        #pragma unroll
        for (int nn = 0; nn < 8; ++nn) {
            int col = wn * 128 + nn * 16 + lr;
            #pragma unroll
            for (int r = 0; r < 4; ++r) {
                int row = bm + wm * 32 + m * 16 + lg * 4 + r;
                C[(size_t)row * NCOLS + col] = __float2half(acc[m][nn][r]);
            }
        }
    }
}

// ------- scores v3: one THREAD per node, v-table in LDS (broadcast reads) ---------
// s[n, 0..3] = src-head scores, s[n, 4..7] = dst-head scores
template <int K>
__global__ __launch_bounds__(256) void scores3_kernel(const __half* __restrict__ x,
                                                      const float* __restrict__ v,
                                                      float* __restrict__ ssrc,
                                                      float* __restrict__ sdst) {
    __shared__ float vs[K * 8];
    int t = threadIdx.x;
    for (int i = t; i < K * 8; i += 256) vs[i] = v[i];
    __syncthreads();
    int node = blockIdx.x * 256 + t;
    if (node >= N_NODES) return;
    const __half* xr = x + (size_t)node * K;
    f32x4 as = {0.f, 0.f, 0.f, 0.f};
    f32x4 ad = {0.f, 0.f, 0.f, 0.f};
    #pragma unroll 4
    for (int k0 = 0; k0 < K; k0 += 8) {
        uint4 u = *(const uint4*)(xr + k0);
        __half2* hp = (__half2*)&u;
        #pragma unroll
        for (int q = 0; q < 4; ++q) {
            float2 f = __half22float2(hp[q]);
            int k = k0 + 2 * q;
            f32x4 va0 = *(const f32x4*)&vs[k * 8];
            f32x4 vd0 = *(const f32x4*)&vs[k * 8 + 4];
            f32x4 va1 = *(const f32x4*)&vs[(k + 1) * 8];
            f32x4 vd1 = *(const f32x4*)&vs[(k + 1) * 8 + 4];
            as += f.x * va0;
            as += f.y * va1;
            ad += f.x * vd0;
            ad += f.y * vd1;
        }
    }
    *(f32x4*)(ssrc + node * 4) = as;
    *(f32x4*)(sdst + node * 4) = ad;
}

// ---- wave-per-node aggregate (r6 config: one block per 4-node group) ----
__device__ __forceinline__ void accum8(float* acc, uint4 u, float a) {
    __half2* hp = (__half2*)&u;
    #pragma unroll
    for (int q = 0; q < 4; ++q) {
        float2 f = __half22float2(hp[q]);
        acc[2 * q]     += a * f.x;
        acc[2 * q + 1] += a * f.y;
    }
}

__global__ __launch_bounds__(256) void aggregate_kernel(const __half* __restrict__ xh,
                                                        const float* __restrict__ s_src,
                                                        const float* __restrict__ s_dst,
                                                        const int* __restrict__ offsets,
                                                        const int* __restrict__ csr_src,
                                                        const float* __restrict__ bias,
                                                        const float* __restrict__ gamma,
                                                        const float* __restrict__ beta,
                                                        __half* __restrict__ h16out) {
    int wv = threadIdx.x >> 6;
    int lane = threadIdx.x & 63;
    int n = blockIdx.x * 4 + wv;
    if (n >= N_NODES) return;
    int start = offsets[n], end = offsets[n + 1];
    int deg = end - start;
    const float4 sd = *(const float4*)(s_dst + n * 4);
    int myh = lane >> 4;

    __shared__ int   srcs[4][64];
    __shared__ float alpha[4][64][4];

    float acc[8] = {};
    const char* xb = (const char*)xh + lane * 16;   // lane covers halves [lane*8, lane*8+8)

    if (deg <= 64) {
        bool act = lane < deg;
        int src = act ? csr_src[start + lane] : 0;
        float4 ss = *(const float4*)(s_src + src * 4);
        float e0 = act ? lrelu(ss.x + sd.x) : -1e30f;
        float e1 = act ? lrelu(ss.y + sd.y) : -1e30f;
        float e2 = act ? lrelu(ss.z + sd.z) : -1e30f;
        float e3 = act ? lrelu(ss.w + sd.w) : -1e30f;
        float m0 = e0, m1 = e1, m2 = e2, m3 = e3;
        #pragma unroll
        for (int o = 32; o > 0; o >>= 1) {
            m0 = fmaxf(m0, __shfl_xor(m0, o));
            m1 = fmaxf(m1, __shfl_xor(m1, o));
            m2 = fmaxf(m2, __shfl_xor(m2, o));
            m3 = fmaxf(m3, __shfl_xor(m3, o));
        }
        float p0 = __expf(e0 - m0), p1 = __expf(e1 - m1);
        float p2 = __expf(e2 - m2), p3 = __expf(e3 - m3);
        float s0 = p0, s1 = p1, s2 = p2, s3 = p3;
        #pragma unroll
        for (int o = 32; o > 0; o >>= 1) {
            s0 += __shfl_xor(s0, o);
            s1 += __shfl_xor(s1, o);
            s2 += __shfl_xor(s2, o);
            s3 += __shfl_xor(s3, o);
        }
        f32x4 av = {p0 / s0, p1 / s1, p2 / s2, p3 / s3};
        srcs[wv][lane] = src;
        *(f32x4*)&alpha[wv][lane][0] = av;
        wave_lds_fence();

        int j = 0;
        for (; j + 4 <= deg; j += 4) {
            uint o0 = (uint)srcs[wv][j]     << 10;
            uint o1 = (uint)srcs[wv][j + 1] << 10;
            uint o2 = (uint)srcs[wv][j + 2] << 10;
            uint o3 = (uint)srcs[wv][j + 3] << 10;
            float a0 = alpha[wv][j][myh];
            float a1 = alpha[wv][j + 1][myh];
            float a2 = alpha[wv][j + 2][myh];
            float a3 = alpha[wv][j + 3][myh];
            uint4 u0 = *(const uint4*)(xb + o0);
            uint4 u1 = *(const uint4*)(xb + o1);
            uint4 u2 = *(const uint4*)(xb + o2);
            uint4 u3 = *(const uint4*)(xb + o3);
            accum8(acc, u0, a0);
            accum8(acc, u1, a1);
            accum8(acc, u2, a2);
            accum8(acc, u3, a3);
        }
        for (; j < deg; ++j) {
            uint o0 = (uint)srcs[wv][j] << 10;
            float a0 = alpha[wv][j][myh];
            uint4 u0 = *(const uint4*)(xb + o0);
            accum8(acc, u0, a0);
        }
    } else {
        // generic chunked path (deg > 64): 3 passes over edges
        float m0 = -1e30f, m1 = -1e30f, m2 = -1e30f, m3 = -1e30f;
        for (int j0 = 0; j0 < deg; j0 += 64) {
            int j = j0 + lane;
            bool act = j < deg;
            int src = act ? csr_src[start + j] : 0;
            float4 ss = *(const float4*)(s_src + src * 4);
            m0 = fmaxf(m0, act ? lrelu(ss.x + sd.x) : -1e30f);
            m1 = fmaxf(m1, act ? lrelu(ss.y + sd.y) : -1e30f);
            m2 = fmaxf(m2, act ? lrelu(ss.z + sd.z) : -1e30f);
            m3 = fmaxf(m3, act ? lrelu(ss.w + sd.w) : -1e30f);
        }
        #pragma unroll
        for (int o = 32; o > 0; o >>= 1) {
            m0 = fmaxf(m0, __shfl_xor(m0, o));
            m1 = fmaxf(m1, __shfl_xor(m1, o));
            m2 = fmaxf(m2, __shfl_xor(m2, o));
            m3 = fmaxf(m3, __shfl_xor(m3, o));
        }
        float s0 = 0.f, s1 = 0.f, s2 = 0.f, s3 = 0.f;
        for (int j0 = 0; j0 < deg; j0 += 64) {
            int j = j0 + lane;
            bool act = j < deg;
            int src = act ? csr_src[start + j] : 0;
            float4 ss = *(const float4*)(s_src + src * 4);
            s0 += act ? __expf(lrelu(ss.x + sd.x) - m0) : 0.f;
            s1 += act ? __expf(lrelu(ss.y + sd.y) - m1) : 0.f;
            s2 += act ? __expf(lrelu(ss.z + sd.z) - m2) : 0.f;
            s3 += act ? __expf(lrelu(ss.w + sd.w) - m3) : 0.f;
        }
        #pragma unroll
        for (int o = 32; o > 0; o >>= 1) {
            s0 += __shfl_xor(s0, o);
            s1 += __shfl_xor(s1, o);
            s2 += __shfl_xor(s2, o);
            s3 += __shfl_xor(s3, o);
        }
        float i0 = 1.f / s0, i1 = 1.f / s1, i2 = 1.f / s2, i3 = 1.f / s3;
        for (int j0 = 0; j0 < deg; j0 += 64) {
            int j = j0 + lane;
            bool act = j < deg;
            int src = act ? csr_src[start + j] : 0;
            float4 ss = *(const float4*)(s_src + src * 4);
            f32x4 av;
            av[0] = act ? __expf(lrelu(ss.x + sd.x) - m0) * i0 : 0.f;
            av[1] = act ? __expf(lrelu(ss.y + sd.y) - m1) * i1 : 0.f;
            av[2] = act ? __expf(lrelu(ss.z + sd.z) - m2) * i2 : 0.f;
            av[3] = act ? __expf(lrelu(ss.w + sd.w) - m3) * i3 : 0.f;
            srcs[wv][lane] = src;
            *(f32x4*)&alpha[wv][lane][0] = av;
            wave_lds_fence();
            int cend = min(64, deg - j0);
            for (int jj = 0; jj < cend; ++jj) {
                uint o0 = (uint)srcs[wv][jj] << 10;
                float aa = alpha[wv][jj][myh];
                uint4 ua = *(const uint4*)(xb + o0);
                accum8(acc, ua, aa);
            }
            wave_lds_fence();
        }
    }

    // cross-head mean: lanes {l, l+16, l+32, l+48} hold same channels for heads 0..3
    #pragma unroll
    for (int r = 0; r < 8; ++r) {
        acc[r] += __shfl_xor(acc[r], 16);
        acc[r] += __shfl_xor(acc[r], 32);
    }
    if (lane < 16) {
        int cb = lane * 8;
        ushort us[8];
        #pragma unroll
        for (int r = 0; r < 8; ++r) {
            int c = cb + r;
            float o = acc[r] * 0.25f + bias[c];
            o = o * (gamma[c] * rsqrtf(1.f + 1e-5f)) + beta[c];
            o = fmaxf(o, 0.f);
            us[r] = __half_as_ushort(__float2half(o));
        }
        uint4 pack;
        pack.x = (uint)us[0] | ((uint)us[1] << 16);
        pack.y = (uint)us[2] | ((uint)us[3] << 16);
        pack.z = (uint)us[4] | ((uint)us[5] << 16);
        pack.w = (uint)us[6] | ((uint)us[7] << 16);
        *(uint4*)(h16out + (size_t)n * HID + cb) = pack;
    }
}

// ---------------- pooling (batch sorted -> run-length partial sums) ----------------
__global__ __launch_bounds__(128) void pool_kernel(const __half* __restrict__ h,
                                                   const int* __restrict__ batch,
                                                   float* pooled, float* counts) {
    int t = threadIdx.x;
    int n0 = blockIdx.x * 256;
    int n1 = min(n0 + 256, N_NODES);
    if (n0 >= N_NODES) return;
    int cg = batch[n0];
    float acc = 0.f, cnt = 0.f;
    for (int n = n0; n < n1; ++n) {
        int g = batch[n];
        if (g != cg) {
            atomicAdd(&pooled[cg * HID + t], acc);
            if (t == 0) atomicAdd(&counts[cg], cnt);
            acc = 0.f; cnt = 0.f; cg = g;
        }
        acc += __half2float(h[(size_t)n * HID + t]);
        cnt += 1.f;
    }
    atomicAdd(&pooled[cg * HID + t], acc);
    if (t == 0) atomicAdd(&counts[cg], cnt);
}

// ---------------- head: mean-divide + fc1 + relu + fc2 ----------------
__global__ __launch_bounds__(128) void head_kernel(const float* __restrict__ pooled,
                                                   const float* __restrict__ counts,
                                                   const float* __restrict__ fc1_w,
                                                   const float* __restrict__ fc1_b,
                                                   const float* __restrict__ fc2_w,
                                                   const float* __restrict__ fc2_b,
                                                   float* __restrict__ out) {
    int gI = blockIdx.x;
    int t = threadIdx.x;
    __shared__ float p[HID], hb[HID];
    p[t] = pooled[gI * HID + t] / fmaxf(counts[gI], 1.f);
    __syncthreads();
    float a = fc1_b[t];
    #pragma unroll 4
    for (int k = 0; k < HID; ++k) a += p[k] * fc1_w[k * HID + t];
    hb[t] = fmaxf(a, 0.f);
    __syncthreads();
    if (t < OUTDIM) {
        float o = fc2_b[t];
        #pragma unroll 4
        for (int k = 0; k < HID; ++k) o += hb[k] * fc2_w[k * OUTDIM + t];
        out[gI * OUTDIM + t] = o;
    }
}

extern "C" void kernel_launch(void* const* d_in, const int* in_sizes, int n_in,
                              void* d_out, int out_size, void* d_ws, size_t ws_size,
                              hipStream_t stream) {
    const float* x     = (const float*)d_in[0];
    const int*   ei    = (const int*)d_in[1];
    const int*   batch = (const int*)d_in[2];
    const float* W[3]  = {(const float*)d_in[3],  (const float*)d_in[9],  (const float*)d_in[15]};
    const float* As[3] = {(const float*)d_in[4],  (const float*)d_in[10], (const float*)d_in[16]};
    const float* Ad[3] = {(const float*)d_in[5],  (const float*)d_in[11], (const float*)d_in[17]};
    const float* Bb[3] = {(const float*)d_in[6],  (const float*)d_in[12], (const float*)d_in[18]};
    const float* Gg[3] = {(const float*)d_in[7],  (const float*)d_in[13], (const float*)d_in[19]};
    const float* Be[3] = {(const float*)d_in[8],  (const float*)d_in[14], (const float*)d_in[20]};
    const float* fc1_w = (const float*)d_in[21];
    const float* fc1_b = (const float*)d_in[22];
    const float* fc2_w = (const float*)d_in[23];
    const float* fc2_b = (const float*)d_in[24];

    char* ws = (char*)d_ws;
    size_t off = 0;
    auto alloc = [&](size_t bytes) {
        void* p = ws + off;
        off = (off + bytes + 255) & ~(size_t)255;
        return p;
    };
    __half* xh     = (__half*)alloc((size_t)N_NODES * NCOLS * 2);
    __half* x16    = (__half*)alloc((size_t)N_NODES * FIN * 2);
    __half* h16    = (__half*)alloc((size_t)N_NODES * HID * 2);
    _Float16* WT[3];
    WT[0] = (_Float16*)alloc((size_t)NCOLS * FIN * 2);
    WT[1] = (_Float16*)alloc((size_t)NCOLS * HID * 2);
    WT[2] = (_Float16*)alloc((size_t)NCOLS * HID * 2);
    float* vtab[3];
    vtab[0] = (float*)alloc((size_t)FIN * 8 * 4);
    vtab[1] = (float*)alloc((size_t)HID * 8 * 4);
    vtab[2] = (float*)alloc((size_t)HID * 8 * 4);
    float* ssrc    = (float*)alloc((size_t)N_NODES * HEADS * 4);
    float* sdst    = (float*)alloc((size_t)N_NODES * HEADS * 4);
    int*   deg     = (int*)alloc((size_t)N_NODES * 4);
    int*   offsets = (int*)alloc((size_t)(N_NODES + 1) * 4);
    int*   pos     = (int*)alloc((size_t)N_NODES * 4);
    int*   partial = (int*)alloc((size_t)256 * 4);
    int*   csr     = (int*)alloc((size_t)(N_EDGES + N_NODES) * 4);
    float* pooled  = (float*)alloc((size_t)NGROUPS * HID * 4 + (size_t)NGROUPS * 4);  // counts appended
    float* counts  = pooled + (size_t)NGROUPS * HID;

    // conversions + per-layer score vectors
    f32to16_kernel<<<(N_NODES * FIN / 4 + 255) / 256, 256, 0, stream>>>(x, x16, N_NODES * FIN);
    wconv_kernel<<<dim3((NCOLS * HID / 8 + 255) / 256, 3), 256, 0, stream>>>(
        W[0], W[1], W[2], WT[0], WT[1], WT[2]);
    prep_v_kernel<<<((FIN + 2 * HID) * 8 + 255) / 256, 256, 0, stream>>>(
        W[0], As[0], Ad[0], W[1], As[1], Ad[1], W[2], As[2], Ad[2],
        vtab[0], vtab[1], vtab[2]);

    // CSR by dst (with self loops)
    const int NB = (N_NODES + 255) / 256;   // 157
    hipMemsetAsync(deg, 0, (size_t)N_NODES * 4, stream);
    deg_count_kernel<<<(N_EDGES + 255) / 256, 256, 0, stream>>>(ei, deg);
    scan1_kernel<<<NB, 256, 0, stream>>>(deg, offsets, partial);
    scan2_kernel<<<1, 256, 0, stream>>>(partial, NB);
    scan3_kernel<<<NB, 256, 0, stream>>>(offsets, pos, partial);
    scatter_kernel<<<(N_EDGES + N_NODES + 255) / 256, 256, 0, stream>>>(ei, pos, csr);

    // 3 GAT layers
    const __half* Ain = x16;
    for (int l = 0; l < 3; ++l) {
        int K = (l == 0) ? FIN : HID;
        if (K == 64) {
            gemm_f16_kernel<64><<<N_NODES / 64, 512, 0, stream>>>(Ain, WT[l], xh);
            scores3_kernel<64><<<NB, 256, 0, stream>>>(Ain, vtab[l], ssrc, sdst);
        } else {
            gemm_f16_kernel<128><<<N_NODES / 64, 512, 0, stream>>>(Ain, WT[l], xh);
            scores3_kernel<128><<<NB, 256, 0, stream>>>(Ain, vtab[l], ssrc, sdst);
        }
        aggregate_kernel<<<(N_NODES + 3) / 4, 256, 0, stream>>>(xh, ssrc, sdst, offsets, csr,
                                                                Bb[l], Gg[l], Be[l], h16);
        Ain = h16;
    }

    // global mean pool + MLP head (single fused memset: counts contiguous after pooled)
    hipMemsetAsync(pooled, 0, (size_t)NGROUPS * HID * 4 + (size_t)NGROUPS * 4, stream);
    pool_kernel<<<(N_NODES + 255) / 256, 128, 0, stream>>>(h16, batch, pooled, counts);
    head_kernel<<<NGROUPS, 128, 0, stream>>>(pooled, counts, fc1_w, fc1_b, fc2_w, fc2_b,
                                             (float*)d_out);
}

// Round 9
// 546.964 us; speedup vs baseline: 1.0937x; 1.0456x over previous
//
#include <hip/hip_runtime.h>
#include <hip/hip_fp16.h>
#include <math.h>

#define N_NODES 40000
#define N_EDGES 640000
#define FIN 64
#define HID 128
#define OUTDIM 64
#define HEADS 4
#define NGROUPS 64
#define NCOLS 512   // HEADS*HID

typedef _Float16 half8 __attribute__((ext_vector_type(8)));
typedef float f32x4 __attribute__((ext_vector_type(4)));

__device__ __forceinline__ float lrelu(float x) { return x > 0.f ? x : 0.2f * x; }

__device__ __forceinline__ void wave_lds_fence() {
    asm volatile("s_waitcnt lgkmcnt(0)" ::: "memory");
}

// ---------------- fp32 -> fp16 convert (x only) ----------------
__global__ void f32to16_kernel(const float* __restrict__ src, __half* __restrict__ dst, int n) {
    int i4 = (blockIdx.x * blockDim.x + threadIdx.x) * 4;
    if (i4 < n) {
        float4 v = *(const float4*)(src + i4);
        __half2 a = __floats2half2_rn(v.x, v.y);
        __half2 b = __floats2half2_rn(v.z, v.w);
        *(__half2*)(dst + i4)     = a;
        *(__half2*)(dst + i4 + 2) = b;
    }
}

// ------- fragment-major weight swizzle: W fp32 [K][512] -> Wf fp16 blobs ----------
// blob index = cb*(K/32) + k0g  (cb = col/16, k0g = k0/32), blob = 512 halves (1KB).
// Within blob, lane l holds {W[k0g*32 + (l>>4)*8 + e][cb*16 + (l&15)]}_{e=0..7} at
// halves l*8..l*8+8  => gemm B-fragment load is one coalesced 1KB wave-load.
__global__ void wswz_kernel(const float* __restrict__ W0, const float* __restrict__ W1,
                            const float* __restrict__ W2,
                            _Float16* __restrict__ F0, _Float16* __restrict__ F1,
                            _Float16* __restrict__ F2) {
    int l = blockIdx.y;
    const float* W = (l == 0) ? W0 : (l == 1) ? W1 : W2;
    _Float16* F = (l == 0) ? F0 : (l == 1) ? F1 : F2;
    int K = (l == 0) ? FIN : HID;
    int id = blockIdx.x * 256 + threadIdx.x;
    int total = (NCOLS / 16) * (K / 32) * 64;
    if (id >= total) return;
    int lane = id & 63;
    int blob = id >> 6;
    int nk = K / 32;
    int k0g = blob % nk;
    int cb  = blob / nk;
    int col = cb * 16 + (lane & 15);
    int kb  = k0g * 32 + (lane >> 4) * 8;
    half8 v;
    #pragma unroll
    for (int e = 0; e < 8; ++e)
        v[e] = (_Float16)W[(size_t)(kb + e) * NCOLS + col];
    *(half8*)(F + (size_t)blob * 512 + lane * 8) = v;
}

// ------- scores via linearity: v[k][j] = sum_c W[k, h*128+c]*a_{s|d}[h,c]  (j=sd*4+h)
__global__ void prep_v_kernel(const float* __restrict__ W0, const float* __restrict__ as0, const float* __restrict__ ad0,
                              const float* __restrict__ W1, const float* __restrict__ as1, const float* __restrict__ ad1,
                              const float* __restrict__ W2, const float* __restrict__ as2, const float* __restrict__ ad2,
                              float* __restrict__ v0, float* __restrict__ v1, float* __restrict__ v2) {
    int j = blockIdx.x * blockDim.x + threadIdx.x;
    const float* W; const float* as_; const float* ad_; float* v; int K;
    if (j < FIN * 8)              { W = W0; as_ = as0; ad_ = ad0; v = v0; K = FIN; }
    else if (j < (FIN + HID) * 8) { W = W1; as_ = as1; ad_ = ad1; v = v1; K = HID; j -= FIN * 8; }
    else if (j < (FIN + 2 * HID) * 8) { W = W2; as_ = as2; ad_ = ad2; v = v2; K = HID; j -= (FIN + HID) * 8; }
    else return;
    int k = j >> 3, sd = (j >> 2) & 1, h = j & 3;
    const float* av = sd ? ad_ : as_;
    float acc = 0.f;
    for (int c = 0; c < HID; ++c)
        acc += W[(size_t)k * NCOLS + h * HID + c] * av[h * HID + c];
    v[k * 8 + sd * 4 + h] = acc;
}

// ---------------- CSR build ----------------
__global__ void deg_count_kernel(const int* __restrict__ ei, int* deg) {
    int e = blockIdx.x * blockDim.x + threadIdx.x;
    if (e < N_EDGES) atomicAdd(&deg[ei[N_EDGES + e]], 1);
}

__global__ void scan1_kernel(const int* __restrict__ deg, int* offsets, int* partial) {
    __shared__ int buf[256];
    int t = threadIdx.x;
    int i = blockIdx.x * 256 + t;
    int v = (i < N_NODES) ? deg[i] + 1 : 0;   // +1 = self loop
    buf[t] = v;
    __syncthreads();
    for (int off = 1; off < 256; off <<= 1) {
        int y = (t >= off) ? buf[t - off] : 0;
        __syncthreads();
        buf[t] += y;
        __syncthreads();
    }
    if (i < N_NODES) offsets[i] = buf[t] - v;       // local exclusive
    if (t == 255) partial[blockIdx.x] = buf[255];
}

__global__ void scan2_kernel(int* partial, int nb) {
    __shared__ int buf[256];
    int t = threadIdx.x;
    int v = (t < nb) ? partial[t] : 0;
    buf[t] = v;
    __syncthreads();
    for (int off = 1; off < 256; off <<= 1) {
        int y = (t >= off) ? buf[t - off] : 0;
        __syncthreads();
        buf[t] += y;
        __syncthreads();
    }
    if (t < nb) partial[t] = buf[t] - v;            // exclusive block prefix
}

__global__ void scan3_kernel(int* offsets, int* pos, const int* __restrict__ partial) {
    int i = blockIdx.x * 256 + threadIdx.x;
    if (i < N_NODES) {
        int o = offsets[i] + partial[i >> 8];
        offsets[i] = o;
        pos[i] = o;
    }
    if (i == 0) offsets[N_NODES] = N_EDGES + N_NODES;
}

__global__ void scatter_kernel(const int* __restrict__ ei, int* pos, int* csr_src) {
    int i = blockIdx.x * blockDim.x + threadIdx.x;
    if (i < N_EDGES) {
        int s = ei[i];
        int d = ei[N_EDGES + i];
        csr_src[atomicAdd(&pos[d], 1)] = s;
    } else if (i < N_EDGES + N_NODES) {
        int nn = i - N_EDGES;
        csr_src[atomicAdd(&pos[nn], 1)] = nn;
    }
}

// ------- MFMA GEMM v3: C[M,512] = A16[M,K] @ W[K,512], 64x512 block tile ---------
// 8 waves (2m x 4n). A staged in LDS; B-fragments read from fragment-major Wf:
// each read = one coalesced 1KB wave-load (L1/L2-resident, 64-128KB table).
template <int K>
__global__ __launch_bounds__(512) void gemm_f16_kernel(const __half* __restrict__ A,
                                                       const _Float16* __restrict__ Wf,
                                                       __half* __restrict__ C) {
    __shared__ _Float16 As[64][K + 8];
    int bm = blockIdx.x * 64;
    int t = threadIdx.x;
    int lane = t & 63;
    int w = t >> 6;
    int wm = w >> 2;        // 0..1
    int wn = w & 3;         // 0..3
    int lr = lane & 15;
    int lk = (lane >> 4) * 8;

    if (K == 64) {
        int row = t >> 3, k8 = (t & 7) * 8;
        uint4 av = *(const uint4*)(A + (size_t)(bm + row) * 64 + k8);
        *(uint4*)&As[row][k8] = av;
    } else {  // K == 128
        int row = t >> 4, k8 = (t & 15) * 8;
        #pragma unroll
        for (int rr = 0; rr < 64; rr += 32) {
            uint4 av = *(const uint4*)(A + (size_t)(bm + row + rr) * 128 + k8);
            *(uint4*)&As[row + rr][k8] = av;
        }
    }
    __syncthreads();

    constexpr int NK = K / 32;
    f32x4 acc[2][8] = {};
    #pragma unroll
    for (int k0g = 0; k0g < NK; ++k0g) {
        half8 af0 = *(const half8*)&As[wm * 32 + lr][k0g * 32 + lk];
        half8 af1 = *(const half8*)&As[wm * 32 + 16 + lr][k0g * 32 + lk];
        #pragma unroll
        for (int nn = 0; nn < 8; ++nn) {
            int cb = wn * 8 + nn;
            half8 bf = *(const half8*)(Wf + ((size_t)(cb * NK + k0g) << 9) + lane * 8);
            acc[0][nn] = __builtin_amdgcn_mfma_f32_16x16x32_f16(af0, bf, acc[0][nn], 0, 0, 0);
            acc[1][nn] = __builtin_amdgcn_mfma_f32_16x16x32_f16(af1, bf, acc[1][nn], 0, 0, 0);
        }
    }

    int lg = lane >> 4;
    #pragma unroll
    for (int m = 0; m < 2; ++m) {
        #pragma unroll
        for (int nn = 0; nn < 8; ++nn) {
            int col = wn * 128 + nn * 16 + lr;
            #pragma unroll
            for (int r = 0; r < 4; ++r) {
                int row = bm + wm * 32 + m * 16 + lg * 4 + r;
                C[(size_t)row * NCOLS + col] = __float2half(acc[m][nn][r]);
            }
        }
    }
}

// ------- scores v3: one THREAD per node, v-table in LDS (broadcast reads) ---------
template <int K>
__global__ __launch_bounds__(256) void scores3_kernel(const __half* __restrict__ x,
                                                      const float* __restrict__ v,
                                                      float* __restrict__ ssrc,
                                                      float* __restrict__ sdst) {
    __shared__ float vs[K * 8];
    int t = threadIdx.x;
    for (int i = t; i < K * 8; i += 256) vs[i] = v[i];
    __syncthreads();
    int node = blockIdx.x * 256 + t;
    if (node >= N_NODES) return;
    const __half* xr = x + (size_t)node * K;
    f32x4 as = {0.f, 0.f, 0.f, 0.f};
    f32x4 ad = {0.f, 0.f, 0.f, 0.f};
    #pragma unroll 4
    for (int k0 = 0; k0 < K; k0 += 8) {
        uint4 u = *(const uint4*)(xr + k0);
        __half2* hp = (__half2*)&u;
        #pragma unroll
        for (int q = 0; q < 4; ++q) {
            float2 f = __half22float2(hp[q]);
            int k = k0 + 2 * q;
            f32x4 va0 = *(const f32x4*)&vs[k * 8];
            f32x4 vd0 = *(const f32x4*)&vs[k * 8 + 4];
            f32x4 va1 = *(const f32x4*)&vs[(k + 1) * 8];
            f32x4 vd1 = *(const f32x4*)&vs[(k + 1) * 8 + 4];
            as += f.x * va0;
            as += f.y * va1;
            ad += f.x * vd0;
            ad += f.y * vd1;
        }
    }
    *(f32x4*)(ssrc + node * 4) = as;
    *(f32x4*)(sdst + node * 4) = ad;
}

// ---- wave-per-node aggregate (one block per 4-node group) ----
__device__ __forceinline__ void accum8(float* acc, uint4 u, float a) {
    __half2* hp = (__half2*)&u;
    #pragma unroll
    for (int q = 0; q < 4; ++q) {
        float2 f = __half22float2(hp[q]);
        acc[2 * q]     += a * f.x;
        acc[2 * q + 1] += a * f.y;
    }
}

__global__ __launch_bounds__(256) void aggregate_kernel(const __half* __restrict__ xh,
                                                        const float* __restrict__ s_src,
                                                        const float* __restrict__ s_dst,
                                                        const int* __restrict__ offsets,
                                                        const int* __restrict__ csr_src,
                                                        const float* __restrict__ bias,
                                                        const float* __restrict__ gamma,
                                                        const float* __restrict__ beta,
                                                        __half* __restrict__ h16out) {
    int wv = threadIdx.x >> 6;
    int lane = threadIdx.x & 63;
    int n = blockIdx.x * 4 + wv;
    if (n >= N_NODES) return;
    int start = offsets[n], end = offsets[n + 1];
    int deg = end - start;
    const float4 sd = *(const float4*)(s_dst + n * 4);
    int myh = lane >> 4;

    __shared__ int   srcs[4][64];
    __shared__ float alpha[4][64][4];

    float acc[8] = {};
    const char* xb = (const char*)xh + lane * 16;   // lane covers halves [lane*8, lane*8+8)

    if (deg <= 64) {
        bool act = lane < deg;
        int src = act ? csr_src[start + lane] : 0;
        float4 ss = *(const float4*)(s_src + src * 4);
        float e0 = act ? lrelu(ss.x + sd.x) : -1e30f;
        float e1 = act ? lrelu(ss.y + sd.y) : -1e30f;
        float e2 = act ? lrelu(ss.z + sd.z) : -1e30f;
        float e3 = act ? lrelu(ss.w + sd.w) : -1e30f;
        float m0 = e0, m1 = e1, m2 = e2, m3 = e3;
        #pragma unroll
        for (int o = 32; o > 0; o >>= 1) {
            m0 = fmaxf(m0, __shfl_xor(m0, o));
            m1 = fmaxf(m1, __shfl_xor(m1, o));
            m2 = fmaxf(m2, __shfl_xor(m2, o));
            m3 = fmaxf(m3, __shfl_xor(m3, o));
        }
        float p0 = __expf(e0 - m0), p1 = __expf(e1 - m1);
        float p2 = __expf(e2 - m2), p3 = __expf(e3 - m3);
        float s0 = p0, s1 = p1, s2 = p2, s3 = p3;
        #pragma unroll
        for (int o = 32; o > 0; o >>= 1) {
            s0 += __shfl_xor(s0, o);
            s1 += __shfl_xor(s1, o);
            s2 += __shfl_xor(s2, o);
            s3 += __shfl_xor(s3, o);
        }
        f32x4 av = {p0 / s0, p1 / s1, p2 / s2, p3 / s3};
        srcs[wv][lane] = src;
        *(f32x4*)&alpha[wv][lane][0] = av;
        wave_lds_fence();

        int j = 0;
        for (; j + 4 <= deg; j += 4) {
            uint o0 = (uint)srcs[wv][j]     << 10;
            uint o1 = (uint)srcs[wv][j + 1] << 10;
            uint o2 = (uint)srcs[wv][j + 2] << 10;
            uint o3 = (uint)srcs[wv][j + 3] << 10;
            float a0 = alpha[wv][j][myh];
            float a1 = alpha[wv][j + 1][myh];
            float a2 = alpha[wv][j + 2][myh];
            float a3 = alpha[wv][j + 3][myh];
            uint4 u0 = *(const uint4*)(xb + o0);
            uint4 u1 = *(const uint4*)(xb + o1);
            uint4 u2 = *(const uint4*)(xb + o2);
            uint4 u3 = *(const uint4*)(xb + o3);
            accum8(acc, u0, a0);
            accum8(acc, u1, a1);
            accum8(acc, u2, a2);
            accum8(acc, u3, a3);
        }
        for (; j < deg; ++j) {
            uint o0 = (uint)srcs[wv][j] << 10;
            float a0 = alpha[wv][j][myh];
            uint4 u0 = *(const uint4*)(xb + o0);
            accum8(acc, u0, a0);
        }
    } else {
        // generic chunked path (deg > 64): 3 passes over edges
        float m0 = -1e30f, m1 = -1e30f, m2 = -1e30f, m3 = -1e30f;
        for (int j0 = 0; j0 < deg; j0 += 64) {
            int j = j0 + lane;
            bool act = j < deg;
            int src = act ? csr_src[start + j] : 0;
            float4 ss = *(const float4*)(s_src + src * 4);
            m0 = fmaxf(m0, act ? lrelu(ss.x + sd.x) : -1e30f);
            m1 = fmaxf(m1, act ? lrelu(ss.y + sd.y) : -1e30f);
            m2 = fmaxf(m2, act ? lrelu(ss.z + sd.z) : -1e30f);
            m3 = fmaxf(m3, act ? lrelu(ss.w + sd.w) : -1e30f);
        }
        #pragma unroll
        for (int o = 32; o > 0; o >>= 1) {
            m0 = fmaxf(m0, __shfl_xor(m0, o));
            m1 = fmaxf(m1, __shfl_xor(m1, o));
            m2 = fmaxf(m2, __shfl_xor(m2, o));
            m3 = fmaxf(m3, __shfl_xor(m3, o));
        }
        float s0 = 0.f, s1 = 0.f, s2 = 0.f, s3 = 0.f;
        for (int j0 = 0; j0 < deg; j0 += 64) {
            int j = j0 + lane;
            bool act = j < deg;
            int src = act ? csr_src[start + j] : 0;
            float4 ss = *(const float4*)(s_src + src * 4);
            s0 += act ? __expf(lrelu(ss.x + sd.x) - m0) : 0.f;
            s1 += act ? __expf(lrelu(ss.y + sd.y) - m1) : 0.f;
            s2 += act ? __expf(lrelu(ss.z + sd.z) - m2) : 0.f;
            s3 += act ? __expf(lrelu(ss.w + sd.w) - m3) : 0.f;
        }
        #pragma unroll
        for (int o = 32; o > 0; o >>= 1) {
            s0 += __shfl_xor(s0, o);
            s1 += __shfl_xor(s1, o);
            s2 += __shfl_xor(s2, o);
            s3 += __shfl_xor(s3, o);
        }
        float i0 = 1.f / s0, i1 = 1.f / s1, i2 = 1.f / s2, i3 = 1.f / s3;
        for (int j0 = 0; j0 < deg; j0 += 64) {
            int j = j0 + lane;
            bool act = j < deg;
            int src = act ? csr_src[start + j] : 0;
            float4 ss = *(const float4*)(s_src + src * 4);
            f32x4 av;
            av[0] = act ? __expf(lrelu(ss.x + sd.x) - m0) * i0 : 0.f;
            av[1] = act ? __expf(lrelu(ss.y + sd.y) - m1) * i1 : 0.f;
            av[2] = act ? __expf(lrelu(ss.z + sd.z) - m2) * i2 : 0.f;
            av[3] = act ? __expf(lrelu(ss.w + sd.w) - m3) * i3 : 0.f;
            srcs[wv][lane] = src;
            *(f32x4*)&alpha[wv][lane][0] = av;
            wave_lds_fence();
            int cend = min(64, deg - j0);
            for (int jj = 0; jj < cend; ++jj) {
                uint o0 = (uint)srcs[wv][jj] << 10;
                float aa = alpha[wv][jj][myh];
                uint4 ua = *(const uint4*)(xb + o0);
                accum8(acc, ua, aa);
            }
            wave_lds_fence();
        }
    }

    // cross-head mean: lanes {l, l+16, l+32, l+48} hold same channels for heads 0..3
    #pragma unroll
    for (int r = 0; r < 8; ++r) {
        acc[r] += __shfl_xor(acc[r], 16);
        acc[r] += __shfl_xor(acc[r], 32);
    }
    if (lane < 16) {
        int cb = lane * 8;
        ushort us[8];
        #pragma unroll
        for (int r = 0; r < 8; ++r) {
            int c = cb + r;
            float o = acc[r] * 0.25f + bias[c];
            o = o * (gamma[c] * rsqrtf(1.f + 1e-5f)) + beta[c];
            o = fmaxf(o, 0.f);
            us[r] = __half_as_ushort(__float2half(o));
        }
        uint4 pack;
        pack.x = (uint)us[0] | ((uint)us[1] << 16);
        pack.y = (uint)us[2] | ((uint)us[3] << 16);
        pack.z = (uint)us[4] | ((uint)us[5] << 16);
        pack.w = (uint)us[6] | ((uint)us[7] << 16);
        *(uint4*)(h16out + (size_t)n * HID + cb) = pack;
    }
}

// ---------------- pooling (batch sorted -> run-length partial sums) ----------------
__global__ __launch_bounds__(128) void pool_kernel(const __half* __restrict__ h,
                                                   const int* __restrict__ batch,
                                                   float* pooled, float* counts) {
    int t = threadIdx.x;
    int n0 = blockIdx.x * 256;
    int n1 = min(n0 + 256, N_NODES);
    if (n0 >= N_NODES) return;
    int cg = batch[n0];
    float acc = 0.f, cnt = 0.f;
    for (int n = n0; n < n1; ++n) {
        int g = batch[n];
        if (g != cg) {
            atomicAdd(&pooled[cg * HID + t], acc);
            if (t == 0) atomicAdd(&counts[cg], cnt);
            acc = 0.f; cnt = 0.f; cg = g;
        }
        acc += __half2float(h[(size_t)n * HID + t]);
        cnt += 1.f;
    }
    atomicAdd(&pooled[cg * HID + t], acc);
    if (t == 0) atomicAdd(&counts[cg], cnt);
}

// ---------------- head: mean-divide + fc1 + relu + fc2 ----------------
__global__ __launch_bounds__(128) void head_kernel(const float* __restrict__ pooled,
                                                   const float* __restrict__ counts,
                                                   const float* __restrict__ fc1_w,
                                                   const float* __restrict__ fc1_b,
                                                   const float* __restrict__ fc2_w,
                                                   const float* __restrict__ fc2_b,
                                                   float* __restrict__ out) {
    int gI = blockIdx.x;
    int t = threadIdx.x;
    __shared__ float p[HID], hb[HID];
    p[t] = pooled[gI * HID + t] / fmaxf(counts[gI], 1.f);
    __syncthreads();
    float a = fc1_b[t];
    #pragma unroll 4
    for (int k = 0; k < HID; ++k) a += p[k] * fc1_w[k * HID + t];
    hb[t] = fmaxf(a, 0.f);
    __syncthreads();
    if (t < OUTDIM) {
        float o = fc2_b[t];
        #pragma unroll 4
        for (int k = 0; k < HID; ++k) o += hb[k] * fc2_w[k * OUTDIM + t];
        out[gI * OUTDIM + t] = o;
    }
}

extern "C" void kernel_launch(void* const* d_in, const int* in_sizes, int n_in,
                              void* d_out, int out_size, void* d_ws, size_t ws_size,
                              hipStream_t stream) {
    const float* x     = (const float*)d_in[0];
    const int*   ei    = (const int*)d_in[1];
    const int*   batch = (const int*)d_in[2];
    const float* W[3]  = {(const float*)d_in[3],  (const float*)d_in[9],  (const float*)d_in[15]};
    const float* As[3] = {(const float*)d_in[4],  (const float*)d_in[10], (const float*)d_in[16]};
    const float* Ad[3] = {(const float*)d_in[5],  (const float*)d_in[11], (const float*)d_in[17]};
    const float* Bb[3] = {(const float*)d_in[6],  (const float*)d_in[12], (const float*)d_in[18]};
    const float* Gg[3] = {(const float*)d_in[7],  (const float*)d_in[13], (const float*)d_in[19]};
    const float* Be[3] = {(const float*)d_in[8],  (const float*)d_in[14], (const float*)d_in[20]};
    const float* fc1_w = (const float*)d_in[21];
    const float* fc1_b = (const float*)d_in[22];
    const float* fc2_w = (const float*)d_in[23];
    const float* fc2_b = (const float*)d_in[24];

    char* ws = (char*)d_ws;
    size_t off = 0;
    auto alloc = [&](size_t bytes) {
        void* p = ws + off;
        off = (off + bytes + 255) & ~(size_t)255;
        return p;
    };
    __half* xh     = (__half*)alloc((size_t)N_NODES * NCOLS * 2);
    __half* x16    = (__half*)alloc((size_t)N_NODES * FIN * 2);
    __half* h16    = (__half*)alloc((size_t)N_NODES * HID * 2);
    _Float16* Wf[3];
    Wf[0] = (_Float16*)alloc((size_t)NCOLS * FIN * 2);
    Wf[1] = (_Float16*)alloc((size_t)NCOLS * HID * 2);
    Wf[2] = (_Float16*)alloc((size_t)NCOLS * HID * 2);
    float* vtab[3];
    vtab[0] = (float*)alloc((size_t)FIN * 8 * 4);
    vtab[1] = (float*)alloc((size_t)HID * 8 * 4);
    vtab[2] = (float*)alloc((size_t)HID * 8 * 4);
    float* ssrc    = (float*)alloc((size_t)N_NODES * HEADS * 4);
    float* sdst    = (float*)alloc((size_t)N_NODES * HEADS * 4);
    int*   deg     = (int*)alloc((size_t)N_NODES * 4);
    int*   offsets = (int*)alloc((size_t)(N_NODES + 1) * 4);
    int*   pos     = (int*)alloc((size_t)N_NODES * 4);
    int*   partial = (int*)alloc((size_t)256 * 4);
    int*   csr     = (int*)alloc((size_t)(N_EDGES + N_NODES) * 4);
    float* pooled  = (float*)alloc((size_t)NGROUPS * HID * 4 + (size_t)NGROUPS * 4);  // counts appended
    float* counts  = pooled + (size_t)NGROUPS * HID;

    // conversions + fragment-major weights + per-layer score vectors
    f32to16_kernel<<<(N_NODES * FIN / 4 + 255) / 256, 256, 0, stream>>>(x, x16, N_NODES * FIN);
    wswz_kernel<<<dim3(((NCOLS / 16) * (HID / 32) * 64 + 255) / 256, 3), 256, 0, stream>>>(
        W[0], W[1], W[2], Wf[0], Wf[1], Wf[2]);
    prep_v_kernel<<<((FIN + 2 * HID) * 8 + 255) / 256, 256, 0, stream>>>(
        W[0], As[0], Ad[0], W[1], As[1], Ad[1], W[2], As[2], Ad[2],
        vtab[0], vtab[1], vtab[2]);

    // CSR by dst (with self loops)
    const int NB = (N_NODES + 255) / 256;   // 157
    hipMemsetAsync(deg, 0, (size_t)N_NODES * 4, stream);
    deg_count_kernel<<<(N_EDGES + 255) / 256, 256, 0, stream>>>(ei, deg);
    scan1_kernel<<<NB, 256, 0, stream>>>(deg, offsets, partial);
    scan2_kernel<<<1, 256, 0, stream>>>(partial, NB);
    scan3_kernel<<<NB, 256, 0, stream>>>(offsets, pos, partial);
    scatter_kernel<<<(N_EDGES + N_NODES + 255) / 256, 256, 0, stream>>>(ei, pos, csr);

    // 3 GAT layers
    const __half* Ain = x16;
    for (int l = 0; l < 3; ++l) {
        int K = (l == 0) ? FIN : HID;
        if (K == 64) {
            gemm_f16_kernel<64><<<N_NODES / 64, 512, 0, stream>>>(Ain, Wf[l], xh);
            scores3_kernel<64><<<NB, 256, 0, stream>>>(Ain, vtab[l], ssrc, sdst);
        } else {
            gemm_f16_kernel<128><<<N_NODES / 64, 512, 0, stream>>>(Ain, Wf[l], xh);
            scores3_kernel<128><<<NB, 256, 0, stream>>>(Ain, vtab[l], ssrc, sdst);
        }
        aggregate_kernel<<<(N_NODES + 3) / 4, 256, 0, stream>>>(xh, ssrc, sdst, offsets, csr,
                                                                Bb[l], Gg[l], Be[l], h16);
        Ain = h16;
    }

    // global mean pool + MLP head (single fused memset: counts contiguous after pooled)
    hipMemsetAsync(pooled, 0, (size_t)NGROUPS * HID * 4 + (size_t)NGROUPS * 4, stream);
    pool_kernel<<<(N_NODES + 255) / 256, 128, 0, stream>>>(h16, batch, pooled, counts);
    head_kernel<<<NGROUPS, 128, 0, stream>>>(pooled, counts, fc1_w, fc1_b, fc2_w, fc2_b,
                                             (float*)d_out);
}

// Round 10
// 535.032 us; speedup vs baseline: 1.1181x; 1.0223x over previous
//
#include <hip/hip_runtime.h>
#include <hip/hip_fp16.h>
#include <math.h>

#define N_NODES 40000
#define N_EDGES 640000
#define FIN 64
#define HID 128
#define OUTDIM 64
#define HEADS 4
#define NGROUPS 64
#define NCOLS 512   // HEADS*HID

typedef _Float16 half8 __attribute__((ext_vector_type(8)));
typedef float f32x4 __attribute__((ext_vector_type(4)));

__device__ __forceinline__ float lrelu(float x) { return x > 0.f ? x : 0.2f * x; }

__device__ __forceinline__ void wave_lds_fence() {
    asm volatile("s_waitcnt lgkmcnt(0)" ::: "memory");
}

// ---- fused prep: x->fp16 | fragment-major weight swizzle (3 layers) | vtab ----
// id space: [0, 640000) x16 (4 floats each) ; [.., +20480) wswz ; [.., +2560) prep_v
#define PREP_X4   (N_NODES * FIN / 4)                 // 640000
#define PREP_WSWZ 20480                               // 4096 + 8192 + 8192
#define PREP_V    2560                                // (FIN + 2*HID) * 8
__global__ void prep_kernel(const float* __restrict__ x, __half* __restrict__ x16,
                            const float* __restrict__ W0, const float* __restrict__ W1,
                            const float* __restrict__ W2,
                            _Float16* __restrict__ F0, _Float16* __restrict__ F1,
                            _Float16* __restrict__ F2,
                            const float* __restrict__ as0, const float* __restrict__ ad0,
                            const float* __restrict__ as1, const float* __restrict__ ad1,
                            const float* __restrict__ as2, const float* __restrict__ ad2,
                            float* __restrict__ v0, float* __restrict__ v1,
                            float* __restrict__ v2) {
    int id = blockIdx.x * 256 + threadIdx.x;
    if (id < PREP_X4) {
        int i4 = id * 4;
        float4 v = *(const float4*)(x + i4);
        __half2 a = __floats2half2_rn(v.x, v.y);
        __half2 b = __floats2half2_rn(v.z, v.w);
        *(__half2*)(x16 + i4)     = a;
        *(__half2*)(x16 + i4 + 2) = b;
        return;
    }
    id -= PREP_X4;
    if (id < PREP_WSWZ) {
        const float* W; _Float16* F; int K;
        if (id < 4096)       { W = W0; F = F0; K = FIN; }
        else if (id < 12288) { W = W1; F = F1; K = HID; id -= 4096; }
        else                 { W = W2; F = F2; K = HID; id -= 12288; }
        int lane = id & 63;
        int blob = id >> 6;
        int nk = K / 32;
        int k0g = blob % nk;
        int cb  = blob / nk;
        int col = cb * 16 + (lane & 15);
        int kb  = k0g * 32 + (lane >> 4) * 8;
        half8 v;
        #pragma unroll
        for (int e = 0; e < 8; ++e)
            v[e] = (_Float16)W[(size_t)(kb + e) * NCOLS + col];
        *(half8*)(F + (size_t)blob * 512 + lane * 8) = v;
        return;
    }
    id -= PREP_WSWZ;
    if (id < PREP_V) {
        const float* W; const float* as_; const float* ad_; float* v; int j = id;
        if (j < FIN * 8)              { W = W0; as_ = as0; ad_ = ad0; v = v0; }
        else if (j < (FIN + HID) * 8) { W = W1; as_ = as1; ad_ = ad1; v = v1; j -= FIN * 8; }
        else                          { W = W2; as_ = as2; ad_ = ad2; v = v2; j -= (FIN + HID) * 8; }
        int k = j >> 3, sd = (j >> 2) & 1, h = j & 3;
        const float* av = sd ? ad_ : as_;
        float acc = 0.f;
        for (int c = 0; c < HID; ++c)
            acc += W[(size_t)k * NCOLS + h * HID + c] * av[h * HID + c];
        v[k * 8 + sd * 4 + h] = acc;
    }
}

// ---------------- CSR build ----------------
__global__ void deg_count_kernel(const int* __restrict__ ei, int* deg) {
    int e = blockIdx.x * blockDim.x + threadIdx.x;
    if (e < N_EDGES) atomicAdd(&deg[ei[N_EDGES + e]], 1);
}

__global__ void scan1_kernel(const int* __restrict__ deg, int* offsets, int* partial) {
    __shared__ int buf[256];
    int t = threadIdx.x;
    int i = blockIdx.x * 256 + t;
    int v = (i < N_NODES) ? deg[i] + 1 : 0;   // +1 = self loop
    buf[t] = v;
    __syncthreads();
    for (int off = 1; off < 256; off <<= 1) {
        int y = (t >= off) ? buf[t - off] : 0;
        __syncthreads();
        buf[t] += y;
        __syncthreads();
    }
    if (i < N_NODES) offsets[i] = buf[t] - v;       // local exclusive
    if (t == 255) partial[blockIdx.x] = buf[255];
}

__global__ void scan2_kernel(int* partial, int nb) {
    __shared__ int buf[256];
    int t = threadIdx.x;
    int v = (t < nb) ? partial[t] : 0;
    buf[t] = v;
    __syncthreads();
    for (int off = 1; off < 256; off <<= 1) {
        int y = (t >= off) ? buf[t - off] : 0;
        __syncthreads();
        buf[t] += y;
        __syncthreads();
    }
    if (t < nb) partial[t] = buf[t] - v;            // exclusive block prefix
}

__global__ void scan3_kernel(int* offsets, int* pos, const int* __restrict__ partial) {
    int i = blockIdx.x * 256 + threadIdx.x;
    if (i < N_NODES) {
        int o = offsets[i] + partial[i >> 8];
        offsets[i] = o;
        pos[i] = o;
    }
    if (i == 0) offsets[N_NODES] = N_EDGES + N_NODES;
}

__global__ void scatter_kernel(const int* __restrict__ ei, int* pos, int* csr_src) {
    int i = blockIdx.x * blockDim.x + threadIdx.x;
    if (i < N_EDGES) {
        int s = ei[i];
        int d = ei[N_EDGES + i];
        csr_src[atomicAdd(&pos[d], 1)] = s;
    } else if (i < N_EDGES + N_NODES) {
        int nn = i - N_EDGES;
        csr_src[atomicAdd(&pos[nn], 1)] = nn;
    }
}

// ------- MFMA GEMM v4: C[M,512] = A16[M,K] @ W[K,512], 64x512 block tile ---------
// 8 waves (2m x 4n). A in LDS; B from fragment-major Wf (coalesced 1KB wave-loads).
// NEW: scores fused in epilogue (from As + vtab-in-LDS); C-write staged through a
// row-major LDS buffer in 2 rounds -> half8 (16B) coalesced stores.
template <int K>
__global__ __launch_bounds__(512) void gemm_f16_kernel(const __half* __restrict__ A,
                                                       const _Float16* __restrict__ Wf,
                                                       const float* __restrict__ vtab,
                                                       __half* __restrict__ C,
                                                       float* __restrict__ ssrc,
                                                       float* __restrict__ sdst) {
    __shared__ _Float16 As[64][K + 8];
    __shared__ _Float16 tb[64][264];     // C staging: 64 rows x 256 cols (+pad)
    __shared__ float vs[K * 8];
    int bm = blockIdx.x * 64;
    int t = threadIdx.x;
    int lane = t & 63;
    int w = t >> 6;
    int wm = w >> 2;        // 0..1
    int wn = w & 3;         // 0..3
    int lr = lane & 15;
    int lk = (lane >> 4) * 8;

    for (int i = t; i < K * 8; i += 512) vs[i] = vtab[i];
    if (K == 64) {
        int row = t >> 3, k8 = (t & 7) * 8;
        uint4 av = *(const uint4*)(A + (size_t)(bm + row) * 64 + k8);
        *(uint4*)&As[row][k8] = av;
    } else {  // K == 128
        int row = t >> 4, k8 = (t & 15) * 8;
        #pragma unroll
        for (int rr = 0; rr < 64; rr += 32) {
            uint4 av = *(const uint4*)(A + (size_t)(bm + row + rr) * 128 + k8);
            *(uint4*)&As[row + rr][k8] = av;
        }
    }
    __syncthreads();

    constexpr int NK = K / 32;
    f32x4 acc[2][8] = {};
    #pragma unroll
    for (int k0g = 0; k0g < NK; ++k0g) {
        half8 af0 = *(const half8*)&As[wm * 32 + lr][k0g * 32 + lk];
        half8 af1 = *(const half8*)&As[wm * 32 + 16 + lr][k0g * 32 + lk];
        #pragma unroll
        for (int nn = 0; nn < 8; ++nn) {
            int cb = wn * 8 + nn;
            half8 bf = *(const half8*)(Wf + ((size_t)(cb * NK + k0g) << 9) + lane * 8);
            acc[0][nn] = __builtin_amdgcn_mfma_f32_16x16x32_f16(af0, bf, acc[0][nn], 0, 0, 0);
            acc[1][nn] = __builtin_amdgcn_mfma_f32_16x16x32_f16(af1, bf, acc[1][nn], 0, 0, 0);
        }
    }

    // ---- fused scores: node = t>>3 (64 nodes), j = t&7 (4 src + 4 dst heads) ----
    {
        int node = t >> 3, j = t & 7;
        float sacc = 0.f;
        #pragma unroll 2
        for (int k0 = 0; k0 < K; k0 += 8) {
            half8 hv = *(const half8*)&As[node][k0];
            #pragma unroll
            for (int e = 0; e < 8; ++e)
                sacc += (float)hv[e] * vs[(k0 + e) * 8 + j];
        }
        if (j < 4) ssrc[(bm + node) * 4 + j] = sacc;
        else       sdst[(bm + node) * 4 + (j - 4)] = sacc;
    }

    // ---- C write: 2 rounds, each stages cols [rnd*256, rnd*256+256) in tb ----
    int lg = lane >> 4;
    #pragma unroll
    for (int rnd = 0; rnd < 2; ++rnd) {
        __syncthreads();
        if ((wn >> 1) == rnd) {
            int cbase = (wn & 1) * 128;
            #pragma unroll
            for (int m = 0; m < 2; ++m) {
                int row = wm * 32 + m * 16 + lg * 4;
                #pragma unroll
                for (int nn = 0; nn < 8; ++nn) {
                    int col = cbase + nn * 16 + lr;
                    #pragma unroll
                    for (int r = 0; r < 4; ++r)
                        tb[row + r][col] = (_Float16)acc[m][nn][r];
                }
            }
        }
        __syncthreads();
        {
            int row = t >> 3;
            int c0 = (t & 7) * 32;
            half8 v0 = *(const half8*)&tb[row][c0];
            half8 v1 = *(const half8*)&tb[row][c0 + 8];
            half8 v2 = *(const half8*)&tb[row][c0 + 16];
            half8 v3 = *(const half8*)&tb[row][c0 + 24];
            _Float16* cp = (_Float16*)C + (size_t)(bm + row) * NCOLS + rnd * 256 + c0;
            *(half8*)(cp)      = v0;
            *(half8*)(cp + 8)  = v1;
            *(half8*)(cp + 16) = v2;
            *(half8*)(cp + 24) = v3;
        }
    }
}

// ---- wave-per-node aggregate (one block per 4-node group) ----
__device__ __forceinline__ void accum8(float* acc, uint4 u, float a) {
    __half2* hp = (__half2*)&u;
    #pragma unroll
    for (int q = 0; q < 4; ++q) {
        float2 f = __half22float2(hp[q]);
        acc[2 * q]     += a * f.x;
        acc[2 * q + 1] += a * f.y;
    }
}

__global__ __launch_bounds__(256) void aggregate_kernel(const __half* __restrict__ xh,
                                                        const float* __restrict__ s_src,
                                                        const float* __restrict__ s_dst,
                                                        const int* __restrict__ offsets,
                                                        const int* __restrict__ csr_src,
                                                        const float* __restrict__ bias,
                                                        const float* __restrict__ gamma,
                                                        const float* __restrict__ beta,
                                                        __half* __restrict__ h16out) {
    int wv = threadIdx.x >> 6;
    int lane = threadIdx.x & 63;
    int n = blockIdx.x * 4 + wv;
    if (n >= N_NODES) return;
    int start = offsets[n], end = offsets[n + 1];
    int deg = end - start;
    const float4 sd = *(const float4*)(s_dst + n * 4);
    int myh = lane >> 4;

    __shared__ int   srcs[4][64];
    __shared__ float alpha[4][64][4];

    float acc[8] = {};
    const char* xb = (const char*)xh + lane * 16;   // lane covers halves [lane*8, lane*8+8)

    if (deg <= 64) {
        bool act = lane < deg;
        int src = act ? csr_src[start + lane] : 0;
        float4 ss = *(const float4*)(s_src + src * 4);
        float e0 = act ? lrelu(ss.x + sd.x) : -1e30f;
        float e1 = act ? lrelu(ss.y + sd.y) : -1e30f;
        float e2 = act ? lrelu(ss.z + sd.z) : -1e30f;
        float e3 = act ? lrelu(ss.w + sd.w) : -1e30f;
        float m0 = e0, m1 = e1, m2 = e2, m3 = e3;
        #pragma unroll
        for (int o = 32; o > 0; o >>= 1) {
            m0 = fmaxf(m0, __shfl_xor(m0, o));
            m1 = fmaxf(m1, __shfl_xor(m1, o));
            m2 = fmaxf(m2, __shfl_xor(m2, o));
            m3 = fmaxf(m3, __shfl_xor(m3, o));
        }
        float p0 = __expf(e0 - m0), p1 = __expf(e1 - m1);
        float p2 = __expf(e2 - m2), p3 = __expf(e3 - m3);
        float s0 = p0, s1 = p1, s2 = p2, s3 = p3;
        #pragma unroll
        for (int o = 32; o > 0; o >>= 1) {
            s0 += __shfl_xor(s0, o);
            s1 += __shfl_xor(s1, o);
            s2 += __shfl_xor(s2, o);
            s3 += __shfl_xor(s3, o);
        }
        f32x4 av = {p0 / s0, p1 / s1, p2 / s2, p3 / s3};
        srcs[wv][lane] = src;
        *(f32x4*)&alpha[wv][lane][0] = av;
        wave_lds_fence();

        int j = 0;
        for (; j + 4 <= deg; j += 4) {
            uint o0 = (uint)srcs[wv][j]     << 10;
            uint o1 = (uint)srcs[wv][j + 1] << 10;
            uint o2 = (uint)srcs[wv][j + 2] << 10;
            uint o3 = (uint)srcs[wv][j + 3] << 10;
            float a0 = alpha[wv][j][myh];
            float a1 = alpha[wv][j + 1][myh];
            float a2 = alpha[wv][j + 2][myh];
            float a3 = alpha[wv][j + 3][myh];
            uint4 u0 = *(const uint4*)(xb + o0);
            uint4 u1 = *(const uint4*)(xb + o1);
            uint4 u2 = *(const uint4*)(xb + o2);
            uint4 u3 = *(const uint4*)(xb + o3);
            accum8(acc, u0, a0);
            accum8(acc, u1, a1);
            accum8(acc, u2, a2);
            accum8(acc, u3, a3);
        }
        for (; j < deg; ++j) {
            uint o0 = (uint)srcs[wv][j] << 10;
            float a0 = alpha[wv][j][myh];
            uint4 u0 = *(const uint4*)(xb + o0);
            accum8(acc, u0, a0);
        }
    } else {
        // generic chunked path (deg > 64): 3 passes over edges
        float m0 = -1e30f, m1 = -1e30f, m2 = -1e30f, m3 = -1e30f;
        for (int j0 = 0; j0 < deg; j0 += 64) {
            int j = j0 + lane;
            bool act = j < deg;
            int src = act ? csr_src[start + j] : 0;
            float4 ss = *(const float4*)(s_src + src * 4);
            m0 = fmaxf(m0, act ? lrelu(ss.x + sd.x) : -1e30f);
            m1 = fmaxf(m1, act ? lrelu(ss.y + sd.y) : -1e30f);
            m2 = fmaxf(m2, act ? lrelu(ss.z + sd.z) : -1e30f);
            m3 = fmaxf(m3, act ? lrelu(ss.w + sd.w) : -1e30f);
        }
        #pragma unroll
        for (int o = 32; o > 0; o >>= 1) {
            m0 = fmaxf(m0, __shfl_xor(m0, o));
            m1 = fmaxf(m1, __shfl_xor(m1, o));
            m2 = fmaxf(m2, __shfl_xor(m2, o));
            m3 = fmaxf(m3, __shfl_xor(m3, o));
        }
        float s0 = 0.f, s1 = 0.f, s2 = 0.f, s3 = 0.f;
        for (int j0 = 0; j0 < deg; j0 += 64) {
            int j = j0 + lane;
            bool act = j < deg;
            int src = act ? csr_src[start + j] : 0;
            float4 ss = *(const float4*)(s_src + src * 4);
            s0 += act ? __expf(lrelu(ss.x + sd.x) - m0) : 0.f;
            s1 += act ? __expf(lrelu(ss.y + sd.y) - m1) : 0.f;
            s2 += act ? __expf(lrelu(ss.z + sd.z) - m2) : 0.f;
            s3 += act ? __expf(lrelu(ss.w + sd.w) - m3) : 0.f;
        }
        #pragma unroll
        for (int o = 32; o > 0; o >>= 1) {
            s0 += __shfl_xor(s0, o);
            s1 += __shfl_xor(s1, o);
            s2 += __shfl_xor(s2, o);
            s3 += __shfl_xor(s3, o);
        }
        float i0 = 1.f / s0, i1 = 1.f / s1, i2 = 1.f / s2, i3 = 1.f / s3;
        for (int j0 = 0; j0 < deg; j0 += 64) {
            int j = j0 + lane;
            bool act = j < deg;
            int src = act ? csr_src[start + j] : 0;
            float4 ss = *(const float4*)(s_src + src * 4);
            f32x4 av;
            av[0] = act ? __expf(lrelu(ss.x + sd.x) - m0) * i0 : 0.f;
            av[1] = act ? __expf(lrelu(ss.y + sd.y) - m1) * i1 : 0.f;
            av[2] = act ? __expf(lrelu(ss.z + sd.z) - m2) * i2 : 0.f;
            av[3] = act ? __expf(lrelu(ss.w + sd.w) - m3) * i3 : 0.f;
            srcs[wv][lane] = src;
            *(f32x4*)&alpha[wv][lane][0] = av;
            wave_lds_fence();
            int cend = min(64, deg - j0);
            for (int jj = 0; jj < cend; ++jj) {
                uint o0 = (uint)srcs[wv][jj] << 10;
                float aa = alpha[wv][jj][myh];
                uint4 ua = *(const uint4*)(xb + o0);
                accum8(acc, ua, aa);
            }
            wave_lds_fence();
        }
    }

    // cross-head mean: lanes {l, l+16, l+32, l+48} hold same channels for heads 0..3
    #pragma unroll
    for (int r = 0; r < 8; ++r) {
        acc[r] += __shfl_xor(acc[r], 16);
        acc[r] += __shfl_xor(acc[r], 32);
    }
    if (lane < 16) {
        int cb = lane * 8;
        ushort us[8];
        #pragma unroll
        for (int r = 0; r < 8; ++r) {
            int c = cb + r;
            float o = acc[r] * 0.25f + bias[c];
            o = o * (gamma[c] * rsqrtf(1.f + 1e-5f)) + beta[c];
            o = fmaxf(o, 0.f);
            us[r] = __half_as_ushort(__float2half(o));
        }
        uint4 pack;
        pack.x = (uint)us[0] | ((uint)us[1] << 16);
        pack.y = (uint)us[2] | ((uint)us[3] << 16);
        pack.z = (uint)us[4] | ((uint)us[5] << 16);
        pack.w = (uint)us[6] | ((uint)us[7] << 16);
        *(uint4*)(h16out + (size_t)n * HID + cb) = pack;
    }
}

// ------- pooling: 2 nodes in flight, uint (2-channel) loads ----------------
__global__ __launch_bounds__(128) void pool_kernel(const __half* __restrict__ h,
                                                   const int* __restrict__ batch,
                                                   float* pooled, float* counts) {
    int t = threadIdx.x;
    int which = t >> 6;            // 0/1: parity of node within the 256-run
    int c2 = (t & 63) * 2;         // channel pair
    int n0 = blockIdx.x * 256 + which;
    int n1 = min(blockIdx.x * 256 + 256, N_NODES);
    if (n0 >= N_NODES) return;
    int cg = batch[n0];
    float a0 = 0.f, a1 = 0.f, cnt = 0.f;
    for (int n = n0; n < n1; n += 2) {
        int g = batch[n];
        if (g != cg) {
            atomicAdd(&pooled[cg * HID + c2], a0);
            atomicAdd(&pooled[cg * HID + c2 + 1], a1);
            if ((t & 63) == 0) atomicAdd(&counts[cg], cnt);
            a0 = 0.f; a1 = 0.f; cnt = 0.f; cg = g;
        }
        uint u = *(const uint*)(h + (size_t)n * HID + c2);
        __half2 hh = *(__half2*)&u;
        float2 f = __half22float2(hh);
        a0 += f.x; a1 += f.y; cnt += 1.f;
    }
    atomicAdd(&pooled[cg * HID + c2], a0);
    atomicAdd(&pooled[cg * HID + c2 + 1], a1);
    if ((t & 63) == 0) atomicAdd(&counts[cg], cnt);
}

// ---------------- head: mean-divide + fc1 + relu + fc2 ----------------
__global__ __launch_bounds__(128) void head_kernel(const float* __restrict__ pooled,
                                                   const float* __restrict__ counts,
                                                   const float* __restrict__ fc1_w,
                                                   const float* __restrict__ fc1_b,
                                                   const float* __restrict__ fc2_w,
                                                   const float* __restrict__ fc2_b,
                                                   float* __restrict__ out) {
    int gI = blockIdx.x;
    int t = threadIdx.x;
    __shared__ float p[HID], hb[HID];
    p[t] = pooled[gI * HID + t] / fmaxf(counts[gI], 1.f);
    __syncthreads();
    float a = fc1_b[t];
    #pragma unroll 4
    for (int k = 0; k < HID; ++k) a += p[k] * fc1_w[k * HID + t];
    hb[t] = fmaxf(a, 0.f);
    __syncthreads();
    if (t < OUTDIM) {
        float o = fc2_b[t];
        #pragma unroll 4
        for (int k = 0; k < HID; ++k) o += hb[k] * fc2_w[k * OUTDIM + t];
        out[gI * OUTDIM + t] = o;
    }
}

extern "C" void kernel_launch(void* const* d_in, const int* in_sizes, int n_in,
                              void* d_out, int out_size, void* d_ws, size_t ws_size,
                              hipStream_t stream) {
    const float* x     = (const float*)d_in[0];
    const int*   ei    = (const int*)d_in[1];
    const int*   batch = (const int*)d_in[2];
    const float* W[3]  = {(const float*)d_in[3],  (const float*)d_in[9],  (const float*)d_in[15]};
    const float* As[3] = {(const float*)d_in[4],  (const float*)d_in[10], (const float*)d_in[16]};
    const float* Ad[3] = {(const float*)d_in[5],  (const float*)d_in[11], (const float*)d_in[17]};
    const float* Bb[3] = {(const float*)d_in[6],  (const float*)d_in[12], (const float*)d_in[18]};
    const float* Gg[3] = {(const float*)d_in[7],  (const float*)d_in[13], (const float*)d_in[19]};
    const float* Be[3] = {(const float*)d_in[8],  (const float*)d_in[14], (const float*)d_in[20]};
    const float* fc1_w = (const float*)d_in[21];
    const float* fc1_b = (const float*)d_in[22];
    const float* fc2_w = (const float*)d_in[23];
    const float* fc2_b = (const float*)d_in[24];

    char* ws = (char*)d_ws;
    size_t off = 0;
    auto alloc = [&](size_t bytes) {
        void* p = ws + off;
        off = (off + bytes + 255) & ~(size_t)255;
        return p;
    };
    __half* xh     = (__half*)alloc((size_t)N_NODES * NCOLS * 2);
    __half* x16    = (__half*)alloc((size_t)N_NODES * FIN * 2);
    __half* h16    = (__half*)alloc((size_t)N_NODES * HID * 2);
    _Float16* Wf[3];
    Wf[0] = (_Float16*)alloc((size_t)NCOLS * FIN * 2);
    Wf[1] = (_Float16*)alloc((size_t)NCOLS * HID * 2);
    Wf[2] = (_Float16*)alloc((size_t)NCOLS * HID * 2);
    float* vtab[3];
    vtab[0] = (float*)alloc((size_t)FIN * 8 * 4);
    vtab[1] = (float*)alloc((size_t)HID * 8 * 4);
    vtab[2] = (float*)alloc((size_t)HID * 8 * 4);
    float* ssrc    = (float*)alloc((size_t)N_NODES * HEADS * 4);
    float* sdst    = (float*)alloc((size_t)N_NODES * HEADS * 4);
    int*   deg     = (int*)alloc((size_t)N_NODES * 4);
    int*   offsets = (int*)alloc((size_t)(N_NODES + 1) * 4);
    int*   pos     = (int*)alloc((size_t)N_NODES * 4);
    int*   partial = (int*)alloc((size_t)256 * 4);
    int*   csr     = (int*)alloc((size_t)(N_EDGES + N_NODES) * 4);
    float* pooled  = (float*)alloc((size_t)NGROUPS * HID * 4 + (size_t)NGROUPS * 4);  // counts appended
    float* counts  = pooled + (size_t)NGROUPS * HID;

    // fused prep: x16 + fragment-major weights + vtab
    const int PREP_TOTAL = PREP_X4 + PREP_WSWZ + PREP_V;
    prep_kernel<<<(PREP_TOTAL + 255) / 256, 256, 0, stream>>>(
        x, x16, W[0], W[1], W[2], Wf[0], Wf[1], Wf[2],
        As[0], Ad[0], As[1], Ad[1], As[2], Ad[2], vtab[0], vtab[1], vtab[2]);

    // CSR by dst (with self loops)
    const int NB = (N_NODES + 255) / 256;   // 157
    hipMemsetAsync(deg, 0, (size_t)N_NODES * 4, stream);
    deg_count_kernel<<<(N_EDGES + 255) / 256, 256, 0, stream>>>(ei, deg);
    scan1_kernel<<<NB, 256, 0, stream>>>(deg, offsets, partial);
    scan2_kernel<<<1, 256, 0, stream>>>(partial, NB);
    scan3_kernel<<<NB, 256, 0, stream>>>(offsets, pos, partial);
    scatter_kernel<<<(N_EDGES + N_NODES + 255) / 256, 256, 0, stream>>>(ei, pos, csr);

    // 3 GAT layers (gemm computes xh AND scores)
    const __half* Ain = x16;
    for (int l = 0; l < 3; ++l) {
        int K = (l == 0) ? FIN : HID;
        if (K == 64)
            gemm_f16_kernel<64><<<N_NODES / 64, 512, 0, stream>>>(Ain, Wf[l], vtab[l], xh, ssrc, sdst);
        else
            gemm_f16_kernel<128><<<N_NODES / 64, 512, 0, stream>>>(Ain, Wf[l], vtab[l], xh, ssrc, sdst);
        aggregate_kernel<<<(N_NODES + 3) / 4, 256, 0, stream>>>(xh, ssrc, sdst, offsets, csr,
                                                                Bb[l], Gg[l], Be[l], h16);
        Ain = h16;
    }

    // global mean pool + MLP head (single fused memset: counts contiguous after pooled)
    hipMemsetAsync(pooled, 0, (size_t)NGROUPS * HID * 4 + (size_t)NGROUPS * 4, stream);
    pool_kernel<<<(N_NODES + 255) / 256, 128, 0, stream>>>(h16, batch, pooled, counts);
    head_kernel<<<NGROUPS, 128, 0, stream>>>(pooled, counts, fc1_w, fc1_b, fc2_w, fc2_b,
                                             (float*)d_out);
}